// Round 1
// baseline (654.086 us; speedup 1.0000x reference)
//
#include <hip/hip_runtime.h>
#include <hip/hip_bf16.h>
#include <math.h>

#define NB 8
#define TT 2048
#define SS 2048
#define CC 1024
#define EE 1024

typedef __attribute__((ext_vector_type(8))) short short8;
typedef __attribute__((ext_vector_type(4))) float f32x4;

__device__ __forceinline__ unsigned short f2bf(float f) {
  unsigned u = __builtin_bit_cast(unsigned, f);
  u += 0x7fffu + ((u >> 16) & 1u);          // RNE
  return (unsigned short)(u >> 16);
}
__device__ __forceinline__ float bf2f(unsigned short h) {
  unsigned u = ((unsigned)h) << 16;
  return __builtin_bit_cast(float, u);
}

__device__ __forceinline__ void gload16(const void* g, void* l) {
  __builtin_amdgcn_global_load_lds((const __attribute__((address_space(1))) void*)g,
                                   (__attribute__((address_space(3))) void*)l, 16, 0, 0);
}

// ---------------- split f32 -> bf16 hi/lo ----------------
__global__ __launch_bounds__(256) void k_split(const float* __restrict__ in,
    unsigned short* __restrict__ hi, unsigned short* __restrict__ lo, long n4) {
  long i = (long)blockIdx.x * blockDim.x + threadIdx.x;
  long stride = (long)gridDim.x * blockDim.x;
  for (; i < n4; i += stride) {
    float4 v = ((const float4*)in)[i];
    float f[4] = {v.x, v.y, v.z, v.w};
    unsigned short hh[4], ll[4];
#pragma unroll
    for (int j = 0; j < 4; ++j) {
      hh[j] = f2bf(f[j]);
      ll[j] = f2bf(f[j] - bf2f(hh[j]));
    }
    ushort4 h; h.x = hh[0]; h.y = hh[1]; h.z = hh[2]; h.w = hh[3];
    ushort4 l; l.x = ll[0]; l.y = ll[1]; l.z = ll[2]; l.w = ll[3];
    ((ushort4*)hi)[i] = h;
    ((ushort4*)lo)[i] = l;
  }
}

// ---------------- f32 -> bf16 convert ----------------
__global__ __launch_bounds__(256) void k_conv(const float* __restrict__ in,
    unsigned short* __restrict__ out, long n4) {
  long i = (long)blockIdx.x * blockDim.x + threadIdx.x;
  long stride = (long)gridDim.x * blockDim.x;
  for (; i < n4; i += stride) {
    float4 v = ((const float4*)in)[i];
    ushort4 h; h.x = f2bf(v.x); h.y = f2bf(v.y); h.z = f2bf(v.z); h.w = f2bf(v.w);
    ((ushort4*)out)[i] = h;
  }
}

// ---------------- batched transpose f32[R,C] -> bf16 [C,R] (hi (+lo)) ----------------
template <bool SPLIT>
__global__ __launch_bounds__(256) void k_transpose(const float* __restrict__ in,
    unsigned short* __restrict__ hi, unsigned short* __restrict__ lo, int R, int C) {
  __shared__ float tile[64][65];
  int b = blockIdx.z;
  const float* inb = in + (size_t)b * R * C;
  int r0 = blockIdx.y * 64, c0 = blockIdx.x * 64;
  int t = threadIdx.x;
  int tr = t >> 4;            // 0..15
  int tc = (t & 15) * 4;      // 0..60
#pragma unroll
  for (int i = 0; i < 4; ++i) {
    int r = tr + i * 16;
    float4 v = *(const float4*)(inb + (size_t)(r0 + r) * C + (c0 + tc));
    tile[r][tc] = v.x; tile[r][tc + 1] = v.y; tile[r][tc + 2] = v.z; tile[r][tc + 3] = v.w;
  }
  __syncthreads();
  size_t ob = (size_t)b * R * C;
#pragma unroll
  for (int i = 0; i < 4; ++i) {
    int c = tr + i * 16;
    unsigned short hh[4], ll[4];
#pragma unroll
    for (int j = 0; j < 4; ++j) {
      float f = tile[tc + j][c];
      hh[j] = f2bf(f);
      if (SPLIT) ll[j] = f2bf(f - bf2f(hh[j]));
    }
    ushort4 h; h.x = hh[0]; h.y = hh[1]; h.z = hh[2]; h.w = hh[3];
    *(ushort4*)(hi + ob + (size_t)(c0 + c) * R + (r0 + tc)) = h;
    if (SPLIT) {
      ushort4 l; l.x = ll[0]; l.y = ll[1]; l.z = ll[2]; l.w = ll[3];
      *(ushort4*)(lo + ob + (size_t)(c0 + c) * R + (r0 + tc)) = l;
    }
  }
}

// ---------------- GEMM: C[m,n] = sum_k A[m,k] * B[n,k]  (both K-contiguous) ----------------
// EPI: 0 = h epilogue (bias + addend, *scale, split bf16 out)
//      1 = raw f32 out (scores)
//      2 = *scale, bf16 out (pv)
//      3 = bias + addend, *scale, f32 out (final)
template <int EPI, bool SPLIT>
__global__ __launch_bounds__(256, 2) void k_gemm(
    const unsigned short* __restrict__ Ah, const unsigned short* __restrict__ Al,
    const unsigned short* __restrict__ Bh, const unsigned short* __restrict__ Bl,
    int N, int K, long sA, long sB, long sC,
    const float* __restrict__ bias, const float* __restrict__ addend,
    float* __restrict__ outF, unsigned short* __restrict__ outHi,
    unsigned short* __restrict__ outLo, float scale) {
  extern __shared__ unsigned short lds[];
  const int TSZ = 128 * 64;
  unsigned short* ldsAh = lds;
  unsigned short* ldsAl = SPLIT ? (lds + TSZ) : nullptr;
  unsigned short* ldsBh = lds + (SPLIT ? 2 : 1) * TSZ;
  unsigned short* ldsBl = SPLIT ? (lds + 3 * TSZ) : nullptr;

  const int b = blockIdx.z;
  const int tid = threadIdx.x, wave = tid >> 6, lane = tid & 63;
  const int m0 = blockIdx.y * 128, n0 = blockIdx.x * 128;
  const int wm = wave >> 1, wn = wave & 1;

  const unsigned short* gAh = Ah + (size_t)b * sA + (size_t)m0 * K;
  const unsigned short* gAl = SPLIT ? (Al + (size_t)b * sA + (size_t)m0 * K) : nullptr;
  const unsigned short* gBh = Bh + (size_t)b * sB + (size_t)n0 * K;
  const unsigned short* gBl = SPLIT ? (Bl + (size_t)b * sB + (size_t)n0 * K) : nullptr;

  f32x4 acc[4][4] = {};

  const int fragK = (lane >> 4) * 8;
  const int rA = wm * 64 + (lane & 15);
  const int rB = wn * 64 + (lane & 15);

  const int nkt = K >> 6;
  for (int kt = 0; kt < nkt; ++kt) {
    // stage tiles: 128 rows x 64 k bf16 each; linear chunk l=(i*256+tid), row=l>>3, c16=l&7
#pragma unroll
    for (int i = 0; i < 4; ++i) {
      int idx = i * 256 + tid;
      int row = idx >> 3, c16 = idx & 7;
      size_t go = (size_t)row * K + (size_t)kt * 64 + c16 * 8;
      unsigned short* lp0 = ldsAh + (size_t)(i * 256 + wave * 64) * 8;
      gload16(gAh + go, lp0);
      gload16(gBh + go, ldsBh + (size_t)(i * 256 + wave * 64) * 8);
      if (SPLIT) {
        gload16(gAl + go, ldsAl + (size_t)(i * 256 + wave * 64) * 8);
        gload16(gBl + go, ldsBl + (size_t)(i * 256 + wave * 64) * 8);
      }
    }
    __syncthreads();
#pragma unroll
    for (int ks = 0; ks < 2; ++ks) {
      short8 af[4], bfr[4], alf[4], blf[4];
#pragma unroll
      for (int mi = 0; mi < 4; ++mi) {
        int off = (rA + mi * 16) * 64 + ks * 32 + fragK;
        af[mi] = *(const short8*)&ldsAh[off];
        if (SPLIT) alf[mi] = *(const short8*)&ldsAl[off];
      }
#pragma unroll
      for (int ni = 0; ni < 4; ++ni) {
        int off = (rB + ni * 16) * 64 + ks * 32 + fragK;
        bfr[ni] = *(const short8*)&ldsBh[off];
        if (SPLIT) blf[ni] = *(const short8*)&ldsBl[off];
      }
#pragma unroll
      for (int mi = 0; mi < 4; ++mi)
#pragma unroll
        for (int ni = 0; ni < 4; ++ni) {
          acc[mi][ni] = __builtin_amdgcn_mfma_f32_16x16x32_bf16(af[mi], bfr[ni], acc[mi][ni], 0, 0, 0);
          if (SPLIT) {
            acc[mi][ni] = __builtin_amdgcn_mfma_f32_16x16x32_bf16(af[mi], blf[ni], acc[mi][ni], 0, 0, 0);
            acc[mi][ni] = __builtin_amdgcn_mfma_f32_16x16x32_bf16(alf[mi], bfr[ni], acc[mi][ni], 0, 0, 0);
          }
        }
    }
    __syncthreads();
  }

  // epilogue: D[row=(lane>>4)*4+j][col=lane&15]
  const size_t cb = (size_t)b * sC;
  const int mBase = m0 + wm * 64 + ((lane >> 4) << 2);
  const int nBase = n0 + wn * 64 + (lane & 15);
#pragma unroll
  for (int mi = 0; mi < 4; ++mi) {
#pragma unroll
    for (int j = 0; j < 4; ++j) {
      int m = mBase + mi * 16 + j;
#pragma unroll
      for (int ni = 0; ni < 4; ++ni) {
        int n = nBase + ni * 16;
        float v = acc[mi][ni][j];
        size_t o = (size_t)m * N + n;
        if (EPI == 0) {
          v = (v + bias[n] + addend[o]) * scale;
          unsigned short hb = f2bf(v);
          outHi[o] = hb;
          outLo[o] = f2bf(v - bf2f(hb));
        } else if (EPI == 1) {
          outF[cb + o] = v;
        } else if (EPI == 2) {
          outHi[cb + o] = f2bf(v * scale);
        } else {
          outF[o] = (v + bias[n] + addend[o]) * scale;
        }
      }
    }
  }
}

// ---------------- row softmax (in-place f32) + bf16 copy ----------------
__global__ __launch_bounds__(256) void k_softmax(float* __restrict__ attn,
    unsigned short* __restrict__ attn_b, const int* __restrict__ mask) {
  __shared__ float red[8];
  long r = blockIdx.x;              // 0 .. NB*TT-1
  int b = (int)(r >> 11);           // / TT
  float* row = attn + r * (long)SS;
  const int* mrow = mask + (long)b * SS;
  int t = threadIdx.x;
  int base = t * 8;
  float v[8];
  float4 v0 = *(const float4*)(row + base);
  float4 v1 = *(const float4*)(row + base + 4);
  v[0] = v0.x; v[1] = v0.y; v[2] = v0.z; v[3] = v0.w;
  v[4] = v1.x; v[5] = v1.y; v[6] = v1.z; v[7] = v1.w;
  int4 m0i = *(const int4*)(mrow + base);
  int4 m1i = *(const int4*)(mrow + base + 4);
  int mm[8] = {m0i.x, m0i.y, m0i.z, m0i.w, m1i.x, m1i.y, m1i.z, m1i.w};
#pragma unroll
  for (int j = 0; j < 8; ++j) if (mm[j]) v[j] = -INFINITY;
  float mx = v[0];
#pragma unroll
  for (int j = 1; j < 8; ++j) mx = fmaxf(mx, v[j]);
#pragma unroll
  for (int off = 32; off; off >>= 1) mx = fmaxf(mx, __shfl_xor(mx, off));
  int wv = t >> 6, ln = t & 63;
  if (ln == 0) red[wv] = mx;
  __syncthreads();
  mx = fmaxf(fmaxf(red[0], red[1]), fmaxf(red[2], red[3]));
  float sum = 0.f;
#pragma unroll
  for (int j = 0; j < 8; ++j) { v[j] = __expf(v[j] - mx); sum += v[j]; }
#pragma unroll
  for (int off = 32; off; off >>= 1) sum += __shfl_xor(sum, off);
  if (ln == 0) red[4 + wv] = sum;
  __syncthreads();
  sum = (red[4] + red[5]) + (red[6] + red[7]);
  float inv = 1.0f / sum;
#pragma unroll
  for (int j = 0; j < 8; ++j) v[j] *= inv;
  float4 w0; w0.x = v[0]; w0.y = v[1]; w0.z = v[2]; w0.w = v[3];
  float4 w1; w1.x = v[4]; w1.y = v[5]; w1.z = v[6]; w1.w = v[7];
  *(float4*)(row + base) = w0;
  *(float4*)(row + base + 4) = w1;
  unsigned short* brow = attn_b + r * (long)SS + base;
  ushort4 h0; h0.x = f2bf(v[0]); h0.y = f2bf(v[1]); h0.z = f2bf(v[2]); h0.w = f2bf(v[3]);
  ushort4 h1; h1.x = f2bf(v[4]); h1.y = f2bf(v[5]); h1.z = f2bf(v[6]); h1.w = f2bf(v[7]);
  *(ushort4*)(brow) = h0;
  *(ushort4*)(brow + 4) = h1;
}

extern "C" void kernel_launch(void* const* d_in, const int* in_sizes, int n_in,
                              void* d_out, int out_size, void* d_ws, size_t ws_size,
                              hipStream_t stream) {
  (void)in_sizes; (void)n_in; (void)out_size; (void)ws_size;
  const float* x     = (const float*)d_in[0];
  const float* tgt   = (const float*)d_in[1];
  const float* enca  = (const float*)d_in[2];
  const float* encb  = (const float*)d_in[3];
  const int*   mask  = (const int*)d_in[4];
  const float* w_in  = (const float*)d_in[5];
  const float* b_in  = (const float*)d_in[6];
  const float* w_out = (const float*)d_in[7];
  const float* b_out = (const float*)d_in[8];

  float* out  = (float*)d_out;                       // [B,T,C]
  float* attn = out + (size_t)NB * TT * CC;          // [B,T,S]

  char* ws = (char*)d_ws;
  unsigned short* x_hi   = (unsigned short*)(ws + 0);
  unsigned short* x_lo   = (unsigned short*)(ws + 33554432L);
  unsigned short* a_t_hi = (unsigned short*)(ws + 67108864L);
  unsigned short* a_t_lo = (unsigned short*)(ws + 100663296L);
  unsigned short* b_t    = (unsigned short*)(ws + 134217728L);
  unsigned short* h_hi   = (unsigned short*)(ws + 167772160L);
  unsigned short* h_lo   = (unsigned short*)(ws + 201326592L);
  unsigned short* w_in_hi= (unsigned short*)(ws + 234881024L);
  unsigned short* w_in_lo= (unsigned short*)(ws + 236978176L);
  unsigned short* w_out_b= (unsigned short*)(ws + 239075328L);
  // aliases (lifetimes disjoint):
  unsigned short* attn_b = x_hi;   // 64MB region (x_hi+x_lo), dead after GEMM1
  unsigned short* pv     = h_hi;   // 32MB region, dead after scores GEMM

  dim3 blk(256);
  const float S05 = 0.70710678118654752f;

  k_split<<<2048, blk, 0, stream>>>(x, x_hi, x_lo, (long)NB * TT * CC / 4);
  k_split<<<512, blk, 0, stream>>>(w_in, w_in_hi, w_in_lo, (long)EE * CC / 4);
  k_conv<<<512, blk, 0, stream>>>(w_out, w_out_b, (long)CC * EE / 4);
  k_transpose<true><<<dim3(SS / 64, EE / 64, NB), blk, 0, stream>>>(enca, a_t_hi, a_t_lo, EE, SS);
  k_transpose<false><<<dim3(EE / 64, SS / 64, NB), blk, 0, stream>>>(encb, b_t, nullptr, SS, EE);

  // GEMM1: h = (x @ w_in^T + b_in + tgt) * sqrt(0.5), split output
  k_gemm<0, true><<<dim3(EE / 128, (NB * TT) / 128, 1), blk, 65536, stream>>>(
      x_hi, x_lo, w_in_hi, w_in_lo, EE, CC, 0, 0, 0,
      b_in, tgt, nullptr, h_hi, h_lo, S05);

  // scores = h @ enc_a  (batched), raw f32 into attn region
  k_gemm<1, true><<<dim3(SS / 128, TT / 128, NB), blk, 65536, stream>>>(
      h_hi, h_lo, a_t_hi, a_t_lo, SS, EE,
      (long)TT * EE, (long)SS * EE, (long)TT * SS,
      nullptr, nullptr, attn, nullptr, nullptr, 1.0f);

  // masked softmax, in-place, + bf16 copy
  k_softmax<<<NB * TT, blk, 0, stream>>>(attn, attn_b, mask);

  // pv = (attn @ enc_b) * sqrt(S), bf16 out
  k_gemm<2, false><<<dim3(EE / 128, TT / 128, NB), blk, 32768, stream>>>(
      attn_b, nullptr, b_t, nullptr, EE, SS,
      (long)TT * SS, (long)EE * SS, (long)TT * EE,
      nullptr, nullptr, nullptr, pv, nullptr, 45.254833995939045f);

  // out = (pv @ w_out^T + b_out + x) * sqrt(0.5)
  k_gemm<3, false><<<dim3(CC / 128, (NB * TT) / 128, 1), blk, 32768, stream>>>(
      pv, nullptr, w_out_b, nullptr, CC, EE, 0, 0, 0,
      b_out, x, out, nullptr, nullptr, S05);
}

// Round 2
// 596.256 us; speedup vs baseline: 1.0970x; 1.0970x over previous
//
#include <hip/hip_runtime.h>
#include <hip/hip_bf16.h>
#include <math.h>

#define NB 8
#define TT 2048
#define SS 2048
#define CC 1024
#define EE 1024

typedef __attribute__((ext_vector_type(8))) short short8;
typedef __attribute__((ext_vector_type(4))) float f32x4;

__device__ __forceinline__ unsigned short f2bf(float f) {
  unsigned u = __builtin_bit_cast(unsigned, f);
  u += 0x7fffu + ((u >> 16) & 1u);          // RNE
  return (unsigned short)(u >> 16);
}
__device__ __forceinline__ float bf2f(unsigned short h) {
  unsigned u = ((unsigned)h) << 16;
  return __builtin_bit_cast(float, u);
}
__device__ __forceinline__ void gload16(const void* g, void* l) {
  __builtin_amdgcn_global_load_lds((const __attribute__((address_space(1))) void*)g,
                                   (__attribute__((address_space(3))) void*)l, 16, 0, 0);
}
__device__ __forceinline__ unsigned ldsoff(const void* p) {
  return (unsigned)(size_t)(const __attribute__((address_space(3))) char*)p;
}
__device__ __forceinline__ short8 ds128(unsigned off) {
  short8 r;
  asm volatile("ds_read_b128 %0, %1" : "=v"(r) : "v"(off));
  return r;
}
// XOR swizzle: bits 4-6 ^= bits 7-9 (involution; row pair id spreads banks)
__device__ __forceinline__ int swzi(int x) { return x ^ (((x >> 7) & 7) << 4); }

#define WAITV(N) asm volatile("s_waitcnt vmcnt(" #N ")" ::: "memory")
#define WAITL0 asm volatile("s_waitcnt lgkmcnt(0)" ::: "memory")
#define BAR() __builtin_amdgcn_s_barrier()
#define SCH0() __builtin_amdgcn_sched_barrier(0)
#define PRIO1() __builtin_amdgcn_s_setprio(1)
#define PRIO0() __builtin_amdgcn_s_setprio(0)
#define MF(a_, b_, c_) __builtin_amdgcn_mfma_f32_16x16x32_bf16(a_, b_, c_, 0, 0, 0)

// ---------------- split f32 -> bf16 hi/lo ----------------
__global__ __launch_bounds__(256) void k_split(const float* __restrict__ in,
    unsigned short* __restrict__ hi, unsigned short* __restrict__ lo, long n4) {
  long i = (long)blockIdx.x * blockDim.x + threadIdx.x;
  long stride = (long)gridDim.x * blockDim.x;
  for (; i < n4; i += stride) {
    float4 v = ((const float4*)in)[i];
    float f[4] = {v.x, v.y, v.z, v.w};
    unsigned short hh[4], ll[4];
#pragma unroll
    for (int j = 0; j < 4; ++j) {
      hh[j] = f2bf(f[j]);
      ll[j] = f2bf(f[j] - bf2f(hh[j]));
    }
    ushort4 h; h.x = hh[0]; h.y = hh[1]; h.z = hh[2]; h.w = hh[3];
    ushort4 l; l.x = ll[0]; l.y = ll[1]; l.z = ll[2]; l.w = ll[3];
    ((ushort4*)hi)[i] = h;
    ((ushort4*)lo)[i] = l;
  }
}

// ---------------- f32 -> bf16 convert ----------------
__global__ __launch_bounds__(256) void k_conv(const float* __restrict__ in,
    unsigned short* __restrict__ out, long n4) {
  long i = (long)blockIdx.x * blockDim.x + threadIdx.x;
  long stride = (long)gridDim.x * blockDim.x;
  for (; i < n4; i += stride) {
    float4 v = ((const float4*)in)[i];
    ushort4 h; h.x = f2bf(v.x); h.y = f2bf(v.y); h.z = f2bf(v.z); h.w = f2bf(v.w);
    ((ushort4*)out)[i] = h;
  }
}

// ---------------- batched transpose f32[R,C] -> bf16 [C,R] (hi (+lo)) ----------------
template <bool SPLIT>
__global__ __launch_bounds__(256) void k_transpose(const float* __restrict__ in,
    unsigned short* __restrict__ hi, unsigned short* __restrict__ lo, int R, int C) {
  __shared__ float tile[64][65];
  int b = blockIdx.z;
  const float* inb = in + (size_t)b * R * C;
  int r0 = blockIdx.y * 64, c0 = blockIdx.x * 64;
  int t = threadIdx.x;
  int tr = t >> 4;
  int tc = (t & 15) * 4;
#pragma unroll
  for (int i = 0; i < 4; ++i) {
    int r = tr + i * 16;
    float4 v = *(const float4*)(inb + (size_t)(r0 + r) * C + (c0 + tc));
    tile[r][tc] = v.x; tile[r][tc + 1] = v.y; tile[r][tc + 2] = v.z; tile[r][tc + 3] = v.w;
  }
  __syncthreads();
  size_t ob = (size_t)b * R * C;
#pragma unroll
  for (int i = 0; i < 4; ++i) {
    int c = tr + i * 16;
    unsigned short hh[4], ll[4];
#pragma unroll
    for (int j = 0; j < 4; ++j) {
      float f = tile[tc + j][c];
      hh[j] = f2bf(f);
      if (SPLIT) ll[j] = f2bf(f - bf2f(hh[j]));
    }
    ushort4 h; h.x = hh[0]; h.y = hh[1]; h.z = hh[2]; h.w = hh[3];
    *(ushort4*)(hi + ob + (size_t)(c0 + c) * R + (r0 + tc)) = h;
    if (SPLIT) {
      ushort4 l; l.x = ll[0]; l.y = ll[1]; l.z = ll[2]; l.w = ll[3];
      *(ushort4*)(lo + ob + (size_t)(c0 + c) * R + (r0 + tc)) = l;
    }
  }
}

// ================= plain bf16 GEMM, 256x256 tile, BK=64, pipelined =================
// C[m,n] = sum_k A[m,k]*B[n,k]. EPI: 2 = bf16 out (*scale), 3 = f32 out (bias+addend)*scale
// LDS per buffer: A[ks][256][32e] 2x16KB @0, B same @32KB. Two buffers (128KB).
template <int EPI>
__global__ __launch_bounds__(512, 2) void k_gemm8(
    const unsigned short* __restrict__ A, const unsigned short* __restrict__ B,
    int N, int K, long sA, long sB, long sC,
    const float* __restrict__ bias, const float* __restrict__ addend,
    float* __restrict__ outF, unsigned short* __restrict__ outH, float scale) {
  extern __shared__ char lds[];
  const int tid = threadIdx.x, wave = tid >> 6, lane = tid & 63;
  const int b = blockIdx.z;
  const int m0 = blockIdx.y * 256, n0 = blockIdx.x * 256;
  const int wm = wave >> 2, wn = wave & 3;
  const unsigned short* gA = A + (size_t)b * sA + (size_t)m0 * K;
  const unsigned short* gB = B + (size_t)b * sB + (size_t)n0 * K;
  const unsigned ldsB = ldsoff(lds);

  // staging source map (pre-swizzled global): slot s covers lds_lin=(s*512+tid)*16
  int srow[2], sk8[2];
#pragma unroll
  for (int s = 0; s < 2; ++s) {
    int l = swzi((s * 512 + tid) * 16);
    srow[s] = l >> 6;
    sk8[s] = (l >> 4) & 3;
  }
  const int aR = wm * 128 + (lane & 15);
  const int bR = wn * 64 + (lane & 15);
  const int kB = (lane >> 4) * 16;   // byte offset of k-fragment
  const int nkt = K >> 6;

  f32x4 acc[8][4] = {};

  auto STG = [&](int t, int tensor, int ks) {  // tensor 0=A,1=B; ks block
    const unsigned short* g = tensor ? gB : gA;
    char* dst = lds + (t & 1) * 65536 + tensor * 32768 + ks * 16384 + wave * 1024;
    size_t gk = (size_t)t * 64 + ks * 32;
#pragma unroll
    for (int s = 0; s < 2; ++s)
      gload16(g + ((size_t)srow[s] * K + gk + sk8[s] * 8), dst + s * 8192);
  };
  auto RA = [&](int t, int ks, int mf) {
    int lin = (aR + mf * 16) * 64 + kB;
    return ds128(ldsB + (t & 1) * 65536 + ks * 16384 + swzi(lin));
  };
  auto RB = [&](int t, int ks, int nf) {
    int lin = (bR + nf * 16) * 64 + kB;
    return ds128(ldsB + (t & 1) * 65536 + 32768 + ks * 16384 + swzi(lin));
  };

  // prologue: B.ks0(0), A.ks0(0), A.ks1(0), B.ks1(0), B.ks0(1), A.ks0(1)
  STG(0, 1, 0); STG(0, 0, 0); STG(0, 0, 1); STG(0, 1, 1);
  if (nkt > 1) { STG(1, 1, 0); STG(1, 0, 0); }

  for (int u = 0; u < nkt; ++u) {
    if (u + 1 < nkt) { WAITV(8); } else { WAITV(0); }
    BAR();
    short8 bf[4], af[4];
    // ---- ph1: ks0 x mf0-3 ----
#pragma unroll
    for (int nf = 0; nf < 4; ++nf) bf[nf] = RB(u, 0, nf);
#pragma unroll
    for (int mf = 0; mf < 4; ++mf) af[mf] = RA(u, 0, mf);
    if (u + 1 < nkt) { STG(u + 1, 0, 1); STG(u + 1, 1, 1); }
    BAR(); WAITL0; SCH0(); PRIO1();
#pragma unroll
    for (int mf = 0; mf < 4; ++mf)
#pragma unroll
      for (int nf = 0; nf < 4; ++nf) acc[mf][nf] = MF(af[mf], bf[nf], acc[mf][nf]);
    PRIO0(); SCH0(); BAR();
    // ---- ph2: ks0 x mf4-7 ----
#pragma unroll
    for (int mf = 0; mf < 4; ++mf) af[mf] = RA(u, 0, mf + 4);
    if (u + 2 < nkt) STG(u + 2, 1, 0);
    BAR(); WAITL0; SCH0(); PRIO1();
#pragma unroll
    for (int mf = 0; mf < 4; ++mf)
#pragma unroll
      for (int nf = 0; nf < 4; ++nf) acc[mf + 4][nf] = MF(af[mf], bf[nf], acc[mf + 4][nf]);
    PRIO0(); SCH0();
    if (u + 2 < nkt) { WAITV(10); } else if (u + 1 < nkt) { WAITV(8); } else { WAITV(0); }
    BAR();
    // ---- ph3: ks1 x mf0-3 ----
#pragma unroll
    for (int nf = 0; nf < 4; ++nf) bf[nf] = RB(u, 1, nf);
#pragma unroll
    for (int mf = 0; mf < 4; ++mf) af[mf] = RA(u, 1, mf);
    if (u + 2 < nkt) STG(u + 2, 0, 0);
    BAR(); WAITL0; SCH0(); PRIO1();
#pragma unroll
    for (int mf = 0; mf < 4; ++mf)
#pragma unroll
      for (int nf = 0; nf < 4; ++nf) acc[mf][nf] = MF(af[mf], bf[nf], acc[mf][nf]);
    PRIO0(); SCH0(); BAR();
    // ---- ph4: ks1 x mf4-7 ----
#pragma unroll
    for (int mf = 0; mf < 4; ++mf) af[mf] = RA(u, 1, mf + 4);
    BAR(); WAITL0; SCH0(); PRIO1();
#pragma unroll
    for (int mf = 0; mf < 4; ++mf)
#pragma unroll
      for (int nf = 0; nf < 4; ++nf) acc[mf + 4][nf] = MF(af[mf], bf[nf], acc[mf + 4][nf]);
    PRIO0(); SCH0(); BAR();
  }

  const size_t cb = (size_t)b * sC;
  const int mB = m0 + wm * 128 + ((lane >> 4) << 2);
  const int nB = n0 + wn * 64 + (lane & 15);
#pragma unroll
  for (int mf = 0; mf < 8; ++mf)
#pragma unroll
    for (int j = 0; j < 4; ++j) {
      int m = mB + mf * 16 + j;
#pragma unroll
      for (int nf = 0; nf < 4; ++nf) {
        int n = nB + nf * 16;
        float v = acc[mf][nf][j];
        size_t o = (size_t)m * N + n;
        if (EPI == 2) outH[cb + o] = f2bf(v * scale);
        else outF[o] = (v + bias[n] + addend[o]) * scale;
      }
    }
}

// ============ split (hi/lo) GEMM, 128x256 tile, BK=32, 3 products, pipelined ============
// EPI: 0 = h epilogue (bias+addend,*scale, split bf16 out), 1 = raw f32 out (scores)
// LDS per buffer (48KB): A_hi[128][32e]@0 (8KB), A_lo@8K, B_hi[256][32e]@16K, B_lo@32K.
template <int EPI>
__global__ __launch_bounds__(512, 2) void k_split8(
    const unsigned short* __restrict__ Ah, const unsigned short* __restrict__ Al,
    const unsigned short* __restrict__ Bh, const unsigned short* __restrict__ Bl,
    int N, int K, long sA, long sB, long sC,
    const float* __restrict__ bias, const float* __restrict__ addend,
    float* __restrict__ outF, unsigned short* __restrict__ outHi,
    unsigned short* __restrict__ outLo, float scale) {
  extern __shared__ char lds[];
  const int tid = threadIdx.x, wave = tid >> 6, lane = tid & 63;
  const int b = blockIdx.z;
  const int m0 = blockIdx.y * 128, n0 = blockIdx.x * 256;
  const int wm = wave >> 2, wn = wave & 3;
  const unsigned short* gAh = Ah + (size_t)b * sA + (size_t)m0 * K;
  const unsigned short* gAl = Al + (size_t)b * sA + (size_t)m0 * K;
  const unsigned short* gBh = Bh + (size_t)b * sB + (size_t)n0 * K;
  const unsigned short* gBl = Bl + (size_t)b * sB + (size_t)n0 * K;
  const unsigned ldsB = ldsoff(lds);

  int arw, ak8, brw[2], bk8[2];
  { int l = swzi(tid * 16); arw = l >> 6; ak8 = (l >> 4) & 3; }
#pragma unroll
  for (int s = 0; s < 2; ++s) {
    int l = swzi(s * 8192 + tid * 16);
    brw[s] = l >> 6; bk8[s] = (l >> 4) & 3;
  }
  const int aR = wm * 64 + (lane & 15);
  const int bR = wn * 64 + (lane & 15);
  const int kB = (lane >> 4) * 16;
  const int nkt = K >> 5;

  f32x4 acc[4][4] = {};

  auto STG_A = [&](int t, int hilo) {
    const unsigned short* g = hilo ? gAl : gAh;
    char* dst = lds + (t & 1) * 49152 + hilo * 8192 + wave * 1024;
    gload16(g + ((size_t)arw * K + (size_t)t * 32 + ak8 * 8), dst);
  };
  auto STG_B = [&](int t, int hilo, int s) {
    const unsigned short* g = hilo ? gBl : gBh;
    char* dst = lds + (t & 1) * 49152 + 16384 + hilo * 16384 + s * 8192 + wave * 1024;
    gload16(g + ((size_t)brw[s] * K + (size_t)t * 32 + bk8[s] * 8), dst);
  };
  auto RA = [&](int t, int hilo, int mf) {
    int lin = (aR + mf * 16) * 64 + kB;
    return ds128(ldsB + (t & 1) * 49152 + hilo * 8192 + swzi(lin));
  };
  auto RB = [&](int t, int hilo, int nf) {
    int lin = (bR + nf * 16) * 64 + kB;
    return ds128(ldsB + (t & 1) * 49152 + 16384 + hilo * 16384 + swzi(lin));
  };

  // prologue: tile0 units in steady order: A_hi, B_hi0, B_hi1, B_lo0, B_lo1, A_lo
  STG_A(0, 0); STG_B(0, 0, 0); STG_B(0, 0, 1); STG_B(0, 1, 0); STG_B(0, 1, 1); STG_A(0, 1);

  for (int u = 0; u < nkt; ++u) {
    if (u + 1 < nkt) { WAITV(3); } else { WAITV(0); }
    BAR();
    short8 ahi[4], bhi[4], bx[4];
    // ---- ph1: hi*hi ----
#pragma unroll
    for (int nf = 0; nf < 4; ++nf) bhi[nf] = RB(u, 0, nf);
#pragma unroll
    for (int mf = 0; mf < 4; ++mf) ahi[mf] = RA(u, 0, mf);
    if (u + 1 < nkt) { STG_A(u + 1, 0); STG_B(u + 1, 0, 0); }
    BAR(); WAITL0; SCH0(); PRIO1();
#pragma unroll
    for (int mf = 0; mf < 4; ++mf)
#pragma unroll
      for (int nf = 0; nf < 4; ++nf) acc[mf][nf] = MF(ahi[mf], bhi[nf], acc[mf][nf]);
    PRIO0(); SCH0(); WAITV(3); BAR();
    // ---- ph2: hi*lo ----
#pragma unroll
    for (int nf = 0; nf < 4; ++nf) bx[nf] = RB(u, 1, nf);
    if (u + 1 < nkt) { STG_B(u + 1, 0, 1); STG_B(u + 1, 1, 0); }
    BAR(); WAITL0; SCH0(); PRIO1();
#pragma unroll
    for (int mf = 0; mf < 4; ++mf)
#pragma unroll
      for (int nf = 0; nf < 4; ++nf) acc[mf][nf] = MF(ahi[mf], bx[nf], acc[mf][nf]);
    PRIO0(); SCH0(); WAITV(4); BAR();
    // ---- ph3: lo*hi ----
#pragma unroll
    for (int mf = 0; mf < 4; ++mf) bx[mf] = RA(u, 1, mf);
    if (u + 1 < nkt) { STG_B(u + 1, 1, 1); STG_A(u + 1, 1); }
    BAR(); WAITL0; SCH0(); PRIO1();
#pragma unroll
    for (int mf = 0; mf < 4; ++mf)
#pragma unroll
      for (int nf = 0; nf < 4; ++nf) acc[mf][nf] = MF(bx[mf], bhi[nf], acc[mf][nf]);
    PRIO0(); SCH0(); BAR();
  }

  const size_t cb = (size_t)b * sC;
  const int mB = m0 + wm * 64 + ((lane >> 4) << 2);
  const int nB = n0 + wn * 64 + (lane & 15);
#pragma unroll
  for (int mf = 0; mf < 4; ++mf)
#pragma unroll
    for (int j = 0; j < 4; ++j) {
      int m = mB + mf * 16 + j;
#pragma unroll
      for (int nf = 0; nf < 4; ++nf) {
        int n = nB + nf * 16;
        float v = acc[mf][nf][j];
        size_t o = (size_t)m * N + n;
        if (EPI == 0) {
          v = (v + bias[n] + addend[o]) * scale;
          unsigned short hb = f2bf(v);
          outHi[o] = hb;
          outLo[o] = f2bf(v - bf2f(hb));
        } else {
          outF[cb + o] = v;
        }
      }
    }
}

// ---------------- row softmax (in-place f32) + bf16 copy ----------------
__global__ __launch_bounds__(256) void k_softmax(float* __restrict__ attn,
    unsigned short* __restrict__ attn_b, const int* __restrict__ mask) {
  __shared__ float red[8];
  long r = blockIdx.x;
  int b = (int)(r >> 11);
  float* row = attn + r * (long)SS;
  const int* mrow = mask + (long)b * SS;
  int t = threadIdx.x;
  int base = t * 8;
  float v[8];
  float4 v0 = *(const float4*)(row + base);
  float4 v1 = *(const float4*)(row + base + 4);
  v[0] = v0.x; v[1] = v0.y; v[2] = v0.z; v[3] = v0.w;
  v[4] = v1.x; v[5] = v1.y; v[6] = v1.z; v[7] = v1.w;
  int4 m0i = *(const int4*)(mrow + base);
  int4 m1i = *(const int4*)(mrow + base + 4);
  int mm[8] = {m0i.x, m0i.y, m0i.z, m0i.w, m1i.x, m1i.y, m1i.z, m1i.w};
#pragma unroll
  for (int j = 0; j < 8; ++j) if (mm[j]) v[j] = -INFINITY;
  float mx = v[0];
#pragma unroll
  for (int j = 1; j < 8; ++j) mx = fmaxf(mx, v[j]);
#pragma unroll
  for (int off = 32; off; off >>= 1) mx = fmaxf(mx, __shfl_xor(mx, off));
  int wv = t >> 6, ln = t & 63;
  if (ln == 0) red[wv] = mx;
  __syncthreads();
  mx = fmaxf(fmaxf(red[0], red[1]), fmaxf(red[2], red[3]));
  float sum = 0.f;
#pragma unroll
  for (int j = 0; j < 8; ++j) { v[j] = __expf(v[j] - mx); sum += v[j]; }
#pragma unroll
  for (int off = 32; off; off >>= 1) sum += __shfl_xor(sum, off);
  if (ln == 0) red[4 + wv] = sum;
  __syncthreads();
  sum = (red[4] + red[5]) + (red[6] + red[7]);
  float inv = 1.0f / sum;
#pragma unroll
  for (int j = 0; j < 8; ++j) v[j] *= inv;
  float4 w0; w0.x = v[0]; w0.y = v[1]; w0.z = v[2]; w0.w = v[3];
  float4 w1; w1.x = v[4]; w1.y = v[5]; w1.z = v[6]; w1.w = v[7];
  *(float4*)(row + base) = w0;
  *(float4*)(row + base + 4) = w1;
  unsigned short* brow = attn_b + r * (long)SS + base;
  ushort4 h0; h0.x = f2bf(v[0]); h0.y = f2bf(v[1]); h0.z = f2bf(v[2]); h0.w = f2bf(v[3]);
  ushort4 h1; h1.x = f2bf(v[4]); h1.y = f2bf(v[5]); h1.z = f2bf(v[6]); h1.w = f2bf(v[7]);
  *(ushort4*)(brow) = h0;
  *(ushort4*)(brow + 4) = h1;
}

extern "C" void kernel_launch(void* const* d_in, const int* in_sizes, int n_in,
                              void* d_out, int out_size, void* d_ws, size_t ws_size,
                              hipStream_t stream) {
  (void)in_sizes; (void)n_in; (void)out_size; (void)ws_size;
  const float* x     = (const float*)d_in[0];
  const float* tgt   = (const float*)d_in[1];
  const float* enca  = (const float*)d_in[2];
  const float* encb  = (const float*)d_in[3];
  const int*   mask  = (const int*)d_in[4];
  const float* w_in  = (const float*)d_in[5];
  const float* b_in  = (const float*)d_in[6];
  const float* w_out = (const float*)d_in[7];
  const float* b_out = (const float*)d_in[8];

  float* out  = (float*)d_out;                       // [B,T,C]
  float* attn = out + (size_t)NB * TT * CC;          // [B,T,S]

  char* ws = (char*)d_ws;
  unsigned short* x_hi   = (unsigned short*)(ws + 0);
  unsigned short* x_lo   = (unsigned short*)(ws + 33554432L);
  unsigned short* a_t_hi = (unsigned short*)(ws + 67108864L);
  unsigned short* a_t_lo = (unsigned short*)(ws + 100663296L);
  unsigned short* b_t    = (unsigned short*)(ws + 134217728L);
  unsigned short* h_hi   = (unsigned short*)(ws + 167772160L);
  unsigned short* h_lo   = (unsigned short*)(ws + 201326592L);
  unsigned short* w_in_hi= (unsigned short*)(ws + 234881024L);
  unsigned short* w_in_lo= (unsigned short*)(ws + 236978176L);
  unsigned short* w_out_b= (unsigned short*)(ws + 239075328L);
  unsigned short* attn_b = x_hi;   // 64MB region, x dead after GEMM1
  unsigned short* pv     = h_hi;   // 32MB region, h dead after scores GEMM

  hipFuncSetAttribute(reinterpret_cast<const void*>(&k_gemm8<2>),
                      hipFuncAttributeMaxDynamicSharedMemorySize, 131072);
  hipFuncSetAttribute(reinterpret_cast<const void*>(&k_gemm8<3>),
                      hipFuncAttributeMaxDynamicSharedMemorySize, 131072);
  hipFuncSetAttribute(reinterpret_cast<const void*>(&k_split8<0>),
                      hipFuncAttributeMaxDynamicSharedMemorySize, 98304);
  hipFuncSetAttribute(reinterpret_cast<const void*>(&k_split8<1>),
                      hipFuncAttributeMaxDynamicSharedMemorySize, 98304);

  dim3 blk(256), blk512(512);
  const float S05 = 0.70710678118654752f;

  k_split<<<2048, blk, 0, stream>>>(x, x_hi, x_lo, (long)NB * TT * CC / 4);
  k_split<<<512, blk, 0, stream>>>(w_in, w_in_hi, w_in_lo, (long)EE * CC / 4);
  k_conv<<<512, blk, 0, stream>>>(w_out, w_out_b, (long)CC * EE / 4);
  k_transpose<true><<<dim3(SS / 64, EE / 64, NB), blk, 0, stream>>>(enca, a_t_hi, a_t_lo, EE, SS);
  k_transpose<false><<<dim3(EE / 64, SS / 64, NB), blk, 0, stream>>>(encb, b_t, nullptr, SS, EE);

  // GEMM1: h = (x @ w_in^T + b_in + tgt) * sqrt(0.5), split bf16 out
  k_split8<0><<<dim3(EE / 256, (NB * TT) / 128, 1), blk512, 98304, stream>>>(
      x_hi, x_lo, w_in_hi, w_in_lo, EE, CC, 0, 0, 0,
      b_in, tgt, nullptr, h_hi, h_lo, S05);

  // scores = h @ enc_a (batched), raw f32 into attn region
  k_split8<1><<<dim3(SS / 256, TT / 128, NB), blk512, 98304, stream>>>(
      h_hi, h_lo, a_t_hi, a_t_lo, SS, EE,
      (long)TT * EE, (long)SS * EE, (long)TT * SS,
      nullptr, nullptr, attn, nullptr, nullptr, 1.0f);

  // masked softmax, in-place, + bf16 copy
  k_softmax<<<NB * TT, blk, 0, stream>>>(attn, attn_b, mask);

  // pv = (attn @ enc_b) * sqrt(S), bf16 out
  k_gemm8<2><<<dim3(EE / 256, TT / 256, NB), blk512, 131072, stream>>>(
      attn_b, b_t, EE, SS,
      (long)TT * SS, (long)EE * SS, (long)TT * EE,
      nullptr, nullptr, nullptr, pv, 45.254833995939045f);

  // out = (pv @ w_out^T + b_out + x) * sqrt(0.5)
  k_gemm8<3><<<dim3(CC / 256, (NB * TT) / 256, 1), blk512, 131072, stream>>>(
      pv, w_out_b, CC, EE, 0, 0, 0,
      b_out, x, out, nullptr, S05);
}

// Round 3
// 594.802 us; speedup vs baseline: 1.0997x; 1.0024x over previous
//
#include <hip/hip_runtime.h>
#include <hip/hip_bf16.h>
#include <math.h>

#define NB 8
#define TT 2048
#define SS 2048
#define CC 1024
#define EE 1024

typedef __attribute__((ext_vector_type(8))) short short8;
typedef __attribute__((ext_vector_type(4))) float f32x4;

__device__ __forceinline__ unsigned short f2bf(float f) {
  unsigned u = __builtin_bit_cast(unsigned, f);
  u += 0x7fffu + ((u >> 16) & 1u);          // RNE
  return (unsigned short)(u >> 16);
}
__device__ __forceinline__ float bf2f(unsigned short h) {
  unsigned u = ((unsigned)h) << 16;
  return __builtin_bit_cast(float, u);
}
__device__ __forceinline__ void gload16(const void* g, void* l) {
  __builtin_amdgcn_global_load_lds((const __attribute__((address_space(1))) void*)g,
                                   (__attribute__((address_space(3))) void*)l, 16, 0, 0);
}
__device__ __forceinline__ unsigned ldsoff(const void* p) {
  return (unsigned)(size_t)(const __attribute__((address_space(3))) char*)p;
}
__device__ __forceinline__ short8 ds128(unsigned off) {
  short8 r;
  asm volatile("ds_read_b128 %0, %1" : "=v"(r) : "v"(off));
  return r;
}
// XOR swizzle: bits 4-6 ^= bits 7-9 (involution)
__device__ __forceinline__ int swzi(int x) { return x ^ (((x >> 7) & 7) << 4); }

#define WAITV(N) asm volatile("s_waitcnt vmcnt(" #N ")" ::: "memory")
#define WAITL(N) asm volatile("s_waitcnt lgkmcnt(" #N ")" ::: "memory")
#define BAR() __builtin_amdgcn_s_barrier()
#define SCH0() __builtin_amdgcn_sched_barrier(0)
#define PRIO1() __builtin_amdgcn_s_setprio(1)
#define PRIO0() __builtin_amdgcn_s_setprio(0)
#define MF(a_, b_, c_) __builtin_amdgcn_mfma_f32_16x16x32_bf16(a_, b_, c_, 0, 0, 0)

// ---------------- split f32 -> bf16 hi/lo ----------------
__global__ __launch_bounds__(256) void k_split(const float* __restrict__ in,
    unsigned short* __restrict__ hi, unsigned short* __restrict__ lo, long n4) {
  long i = (long)blockIdx.x * blockDim.x + threadIdx.x;
  long stride = (long)gridDim.x * blockDim.x;
  for (; i < n4; i += stride) {
    float4 v = ((const float4*)in)[i];
    float f[4] = {v.x, v.y, v.z, v.w};
    unsigned short hh[4], ll[4];
#pragma unroll
    for (int j = 0; j < 4; ++j) {
      hh[j] = f2bf(f[j]);
      ll[j] = f2bf(f[j] - bf2f(hh[j]));
    }
    ushort4 h; h.x = hh[0]; h.y = hh[1]; h.z = hh[2]; h.w = hh[3];
    ushort4 l; l.x = ll[0]; l.y = ll[1]; l.z = ll[2]; l.w = ll[3];
    ((ushort4*)hi)[i] = h;
    ((ushort4*)lo)[i] = l;
  }
}

// ---------------- f32 -> bf16 convert ----------------
__global__ __launch_bounds__(256) void k_conv(const float* __restrict__ in,
    unsigned short* __restrict__ out, long n4) {
  long i = (long)blockIdx.x * blockDim.x + threadIdx.x;
  long stride = (long)gridDim.x * blockDim.x;
  for (; i < n4; i += stride) {
    float4 v = ((const float4*)in)[i];
    ushort4 h; h.x = f2bf(v.x); h.y = f2bf(v.y); h.z = f2bf(v.z); h.w = f2bf(v.w);
    ((ushort4*)out)[i] = h;
  }
}

// ---------------- batched transpose f32[R,C] -> bf16 [C,R] (hi (+lo)) ----------------
template <bool SPLIT>
__global__ __launch_bounds__(256) void k_transpose(const float* __restrict__ in,
    unsigned short* __restrict__ hi, unsigned short* __restrict__ lo, int R, int C) {
  __shared__ float tile[64][65];
  int b = blockIdx.z;
  const float* inb = in + (size_t)b * R * C;
  int r0 = blockIdx.y * 64, c0 = blockIdx.x * 64;
  int t = threadIdx.x;
  int tr = t >> 4;
  int tc = (t & 15) * 4;
#pragma unroll
  for (int i = 0; i < 4; ++i) {
    int r = tr + i * 16;
    float4 v = *(const float4*)(inb + (size_t)(r0 + r) * C + (c0 + tc));
    tile[r][tc] = v.x; tile[r][tc + 1] = v.y; tile[r][tc + 2] = v.z; tile[r][tc + 3] = v.w;
  }
  __syncthreads();
  size_t ob = (size_t)b * R * C;
#pragma unroll
  for (int i = 0; i < 4; ++i) {
    int c = tr + i * 16;
    unsigned short hh[4], ll[4];
#pragma unroll
    for (int j = 0; j < 4; ++j) {
      float f = tile[tc + j][c];
      hh[j] = f2bf(f);
      if (SPLIT) ll[j] = f2bf(f - bf2f(hh[j]));
    }
    ushort4 h; h.x = hh[0]; h.y = hh[1]; h.z = hh[2]; h.w = hh[3];
    *(ushort4*)(hi + ob + (size_t)(c0 + c) * R + (r0 + tc)) = h;
    if (SPLIT) {
      ushort4 l; l.x = ll[0]; l.y = ll[1]; l.z = ll[2]; l.w = ll[3];
      *(ushort4*)(lo + ob + (size_t)(c0 + c) * R + (r0 + tc)) = l;
    }
  }
}

// ================= plain bf16 GEMM, 256x256 tile, BK=64, pipelined =================
template <int EPI>
__global__ __launch_bounds__(512, 2) void k_gemm8(
    const unsigned short* __restrict__ A, const unsigned short* __restrict__ B,
    int N, int K, long sA, long sB, long sC,
    const float* __restrict__ bias, const float* __restrict__ addend,
    float* __restrict__ outF, unsigned short* __restrict__ outH, float scale) {
  extern __shared__ char lds[];
  const int tid = threadIdx.x, wave = tid >> 6, lane = tid & 63;
  const int b = blockIdx.z;
  const int m0 = blockIdx.y * 256, n0 = blockIdx.x * 256;
  const int wm = wave >> 2, wn = wave & 3;
  const unsigned short* gA = A + (size_t)b * sA + (size_t)m0 * K;
  const unsigned short* gB = B + (size_t)b * sB + (size_t)n0 * K;
  const unsigned ldsB = ldsoff(lds);

  int srow[2], sk8[2];
#pragma unroll
  for (int s = 0; s < 2; ++s) {
    int l = swzi((s * 512 + tid) * 16);
    srow[s] = l >> 6;
    sk8[s] = (l >> 4) & 3;
  }
  const int aR = wm * 128 + (lane & 15);
  const int bR = wn * 64 + (lane & 15);
  const int kB = (lane >> 4) * 16;
  const int nkt = K >> 6;

  f32x4 acc[8][4] = {};

  auto STG = [&](int t, int tensor, int ks) {
    const unsigned short* g = tensor ? gB : gA;
    char* dst = lds + (t & 1) * 65536 + tensor * 32768 + ks * 16384 + wave * 1024;
    size_t gk = (size_t)t * 64 + ks * 32;
#pragma unroll
    for (int s = 0; s < 2; ++s)
      gload16(g + ((size_t)srow[s] * K + gk + sk8[s] * 8), dst + s * 8192);
  };
  auto RA = [&](int t, int ks, int mf) {
    int lin = (aR + mf * 16) * 64 + kB;
    return ds128(ldsB + (t & 1) * 65536 + ks * 16384 + swzi(lin));
  };
  auto RB = [&](int t, int ks, int nf) {
    int lin = (bR + nf * 16) * 64 + kB;
    return ds128(ldsB + (t & 1) * 65536 + 32768 + ks * 16384 + swzi(lin));
  };

  STG(0, 1, 0); STG(0, 0, 0); STG(0, 0, 1); STG(0, 1, 1);
  if (nkt > 1) { STG(1, 1, 0); STG(1, 0, 0); }

  for (int u = 0; u < nkt; ++u) {
    if (u + 1 < nkt) { WAITV(8); } else { WAITV(0); }
    BAR();
    short8 bf[4], af[4];
#pragma unroll
    for (int nf = 0; nf < 4; ++nf) bf[nf] = RB(u, 0, nf);
#pragma unroll
    for (int mf = 0; mf < 4; ++mf) af[mf] = RA(u, 0, mf);
    if (u + 1 < nkt) { STG(u + 1, 0, 1); STG(u + 1, 1, 1); }
    BAR(); WAITL(0); SCH0(); PRIO1();
#pragma unroll
    for (int mf = 0; mf < 4; ++mf)
#pragma unroll
      for (int nf = 0; nf < 4; ++nf) acc[mf][nf] = MF(af[mf], bf[nf], acc[mf][nf]);
    PRIO0(); SCH0(); BAR();
#pragma unroll
    for (int mf = 0; mf < 4; ++mf) af[mf] = RA(u, 0, mf + 4);
    if (u + 2 < nkt) STG(u + 2, 1, 0);
    BAR(); WAITL(0); SCH0(); PRIO1();
#pragma unroll
    for (int mf = 0; mf < 4; ++mf)
#pragma unroll
      for (int nf = 0; nf < 4; ++nf) acc[mf + 4][nf] = MF(af[mf], bf[nf], acc[mf + 4][nf]);
    PRIO0(); SCH0();
    if (u + 2 < nkt) { WAITV(10); } else if (u + 1 < nkt) { WAITV(8); } else { WAITV(0); }
    BAR();
#pragma unroll
    for (int nf = 0; nf < 4; ++nf) bf[nf] = RB(u, 1, nf);
#pragma unroll
    for (int mf = 0; mf < 4; ++mf) af[mf] = RA(u, 1, mf);
    if (u + 2 < nkt) STG(u + 2, 0, 0);
    BAR(); WAITL(0); SCH0(); PRIO1();
#pragma unroll
    for (int mf = 0; mf < 4; ++mf)
#pragma unroll
      for (int nf = 0; nf < 4; ++nf) acc[mf][nf] = MF(af[mf], bf[nf], acc[mf][nf]);
    PRIO0(); SCH0(); BAR();
#pragma unroll
    for (int mf = 0; mf < 4; ++mf) af[mf] = RA(u, 1, mf + 4);
    BAR(); WAITL(0); SCH0(); PRIO1();
#pragma unroll
    for (int mf = 0; mf < 4; ++mf)
#pragma unroll
      for (int nf = 0; nf < 4; ++nf) acc[mf + 4][nf] = MF(af[mf], bf[nf], acc[mf + 4][nf]);
    PRIO0(); SCH0(); BAR();
  }

  const size_t cb = (size_t)b * sC;
  const int mB = m0 + wm * 128 + ((lane >> 4) << 2);
  const int nB = n0 + wn * 64 + (lane & 15);
#pragma unroll
  for (int mf = 0; mf < 8; ++mf)
#pragma unroll
    for (int j = 0; j < 4; ++j) {
      int m = mB + mf * 16 + j;
#pragma unroll
      for (int nf = 0; nf < 4; ++nf) {
        int n = nB + nf * 16;
        float v = acc[mf][nf][j];
        size_t o = (size_t)m * N + n;
        if (EPI == 2) outH[cb + o] = f2bf(v * scale);
        else outF[o] = (v + bias[n] + addend[o]) * scale;
      }
    }
}

// ============ split (hi/lo) GEMM, 128x256 tile, BK=32, 3 products ============
// Single-cluster deep pipeline: 3 LDS buffers (48KB each), prefetch distance 2,
// 1 barrier/tile, all 16 fragments in registers, 48-MFMA setprio cluster.
// EPI: 0 = h epilogue (bias+addend,*scale, split bf16 out), 1 = raw f32 out (scores)
// Buffer layout: A_hi[128][32e]@0 (8KB), A_lo@8K, B_hi[256][32e]@16K, B_lo@32K.
template <int EPI>
__global__ __launch_bounds__(512, 2) void k_split8(
    const unsigned short* __restrict__ Ah, const unsigned short* __restrict__ Al,
    const unsigned short* __restrict__ Bh, const unsigned short* __restrict__ Bl,
    int N, int K, long sA, long sB, long sC,
    const float* __restrict__ bias, const float* __restrict__ addend,
    float* __restrict__ outF, unsigned short* __restrict__ outHi,
    unsigned short* __restrict__ outLo, float scale) {
  extern __shared__ char lds[];
  const int tid = threadIdx.x, wave = tid >> 6, lane = tid & 63;
  const int b = blockIdx.z;
  const int m0 = blockIdx.y * 128, n0 = blockIdx.x * 256;
  const int wm = wave >> 2, wn = wave & 3;
  const unsigned short* gAh = Ah + (size_t)b * sA + (size_t)m0 * K;
  const unsigned short* gAl = Al + (size_t)b * sA + (size_t)m0 * K;
  const unsigned short* gBh = Bh + (size_t)b * sB + (size_t)n0 * K;
  const unsigned short* gBl = Bl + (size_t)b * sB + (size_t)n0 * K;
  const unsigned ldsB = ldsoff(lds);

  int arw, ak8, brw[2], bk8[2];
  { int l = swzi(tid * 16); arw = l >> 6; ak8 = (l >> 4) & 3; }
#pragma unroll
  for (int s = 0; s < 2; ++s) {
    int l = swzi(s * 8192 + tid * 16);
    brw[s] = l >> 6; bk8[s] = (l >> 4) & 3;
  }
  const int aR = wm * 64 + (lane & 15);
  const int bR = wn * 64 + (lane & 15);
  const int kB = (lane >> 4) * 16;
  const int nkt = K >> 5;

  f32x4 acc[4][4] = {};

  auto STG = [&](int t, int bf) {   // 6 gload16 units -> buffer bf
    char* base = lds + bf * 49152;
    size_t gk = (size_t)t * 32;
    gload16(gAh + ((size_t)arw * K + gk + ak8 * 8), base + wave * 1024);
    gload16(gBh + ((size_t)brw[0] * K + gk + bk8[0] * 8), base + 16384 + wave * 1024);
    gload16(gBh + ((size_t)brw[1] * K + gk + bk8[1] * 8), base + 24576 + wave * 1024);
    gload16(gBl + ((size_t)brw[0] * K + gk + bk8[0] * 8), base + 32768 + wave * 1024);
    gload16(gBl + ((size_t)brw[1] * K + gk + bk8[1] * 8), base + 40960 + wave * 1024);
    gload16(gAl + ((size_t)arw * K + gk + ak8 * 8), base + 8192 + wave * 1024);
  };
  auto RA = [&](int bf, int hilo, int mf) {
    int lin = (aR + mf * 16) * 64 + kB;
    return ds128(ldsB + bf * 49152 + hilo * 8192 + swzi(lin));
  };
  auto RB = [&](int bf, int hilo, int nf) {
    int lin = (bR + nf * 16) * 64 + kB;
    return ds128(ldsB + bf * 49152 + 16384 + hilo * 16384 + swzi(lin));
  };

  // prologue: prefetch tiles 0 and 1 (12 units outstanding)
  STG(0, 0);
  STG(1, 1);

  int bc = 0;  // current buffer = u % 3
  for (int u = 0; u < nkt; ++u) {
    if (u + 1 < nkt) { WAITV(6); } else { WAITV(0); }
    BAR();
    short8 ahi[4], bhi[4], alo[4], blo[4];
#pragma unroll
    for (int mf = 0; mf < 4; ++mf) ahi[mf] = RA(bc, 0, mf);
#pragma unroll
    for (int nf = 0; nf < 4; ++nf) bhi[nf] = RB(bc, 0, nf);
#pragma unroll
    for (int mf = 0; mf < 4; ++mf) alo[mf] = RA(bc, 1, mf);
#pragma unroll
    for (int nf = 0; nf < 4; ++nf) blo[nf] = RB(bc, 1, nf);
    if (u + 2 < nkt) {
      int bs = bc + 2; if (bs >= 3) bs -= 3;
      STG(u + 2, bs);
    }
    WAITL(8); SCH0(); PRIO1();
#pragma unroll
    for (int mf = 0; mf < 4; ++mf)
#pragma unroll
      for (int nf = 0; nf < 4; ++nf) acc[mf][nf] = MF(ahi[mf], bhi[nf], acc[mf][nf]);
    WAITL(0); SCH0();
#pragma unroll
    for (int mf = 0; mf < 4; ++mf)
#pragma unroll
      for (int nf = 0; nf < 4; ++nf) {
        acc[mf][nf] = MF(ahi[mf], blo[nf], acc[mf][nf]);
        acc[mf][nf] = MF(alo[mf], bhi[nf], acc[mf][nf]);
      }
    PRIO0(); SCH0();
    bc = (bc == 2) ? 0 : bc + 1;
  }

  const size_t cb = (size_t)b * sC;
  const int mB = m0 + wm * 64 + ((lane >> 4) << 2);
  const int nB = n0 + wn * 64 + (lane & 15);
#pragma unroll
  for (int mf = 0; mf < 4; ++mf)
#pragma unroll
    for (int j = 0; j < 4; ++j) {
      int m = mB + mf * 16 + j;
#pragma unroll
      for (int nf = 0; nf < 4; ++nf) {
        int n = nB + nf * 16;
        float v = acc[mf][nf][j];
        size_t o = (size_t)m * N + n;
        if (EPI == 0) {
          v = (v + bias[n] + addend[o]) * scale;
          unsigned short hb = f2bf(v);
          outHi[o] = hb;
          outLo[o] = f2bf(v - bf2f(hb));
        } else {
          outF[cb + o] = v;
        }
      }
    }
}

// ---------------- row softmax (in-place f32) + bf16 copy ----------------
__global__ __launch_bounds__(256) void k_softmax(float* __restrict__ attn,
    unsigned short* __restrict__ attn_b, const int* __restrict__ mask) {
  __shared__ float red[8];
  long r = blockIdx.x;
  int b = (int)(r >> 11);
  float* row = attn + r * (long)SS;
  const int* mrow = mask + (long)b * SS;
  int t = threadIdx.x;
  int base = t * 8;
  float v[8];
  float4 v0 = *(const float4*)(row + base);
  float4 v1 = *(const float4*)(row + base + 4);
  v[0] = v0.x; v[1] = v0.y; v[2] = v0.z; v[3] = v0.w;
  v[4] = v1.x; v[5] = v1.y; v[6] = v1.z; v[7] = v1.w;
  int4 m0i = *(const int4*)(mrow + base);
  int4 m1i = *(const int4*)(mrow + base + 4);
  int mm[8] = {m0i.x, m0i.y, m0i.z, m0i.w, m1i.x, m1i.y, m1i.z, m1i.w};
#pragma unroll
  for (int j = 0; j < 8; ++j) if (mm[j]) v[j] = -INFINITY;
  float mx = v[0];
#pragma unroll
  for (int j = 1; j < 8; ++j) mx = fmaxf(mx, v[j]);
#pragma unroll
  for (int off = 32; off; off >>= 1) mx = fmaxf(mx, __shfl_xor(mx, off));
  int wv = t >> 6, ln = t & 63;
  if (ln == 0) red[wv] = mx;
  __syncthreads();
  mx = fmaxf(fmaxf(red[0], red[1]), fmaxf(red[2], red[3]));
  float sum = 0.f;
#pragma unroll
  for (int j = 0; j < 8; ++j) { v[j] = __expf(v[j] - mx); sum += v[j]; }
#pragma unroll
  for (int off = 32; off; off >>= 1) sum += __shfl_xor(sum, off);
  if (ln == 0) red[4 + wv] = sum;
  __syncthreads();
  sum = (red[4] + red[5]) + (red[6] + red[7]);
  float inv = 1.0f / sum;
#pragma unroll
  for (int j = 0; j < 8; ++j) v[j] *= inv;
  float4 w0; w0.x = v[0]; w0.y = v[1]; w0.z = v[2]; w0.w = v[3];
  float4 w1; w1.x = v[4]; w1.y = v[5]; w1.z = v[6]; w1.w = v[7];
  *(float4*)(row + base) = w0;
  *(float4*)(row + base + 4) = w1;
  unsigned short* brow = attn_b + r * (long)SS + base;
  ushort4 h0; h0.x = f2bf(v[0]); h0.y = f2bf(v[1]); h0.z = f2bf(v[2]); h0.w = f2bf(v[3]);
  ushort4 h1; h1.x = f2bf(v[4]); h1.y = f2bf(v[5]); h1.z = f2bf(v[6]); h1.w = f2bf(v[7]);
  *(ushort4*)(brow) = h0;
  *(ushort4*)(brow + 4) = h1;
}

extern "C" void kernel_launch(void* const* d_in, const int* in_sizes, int n_in,
                              void* d_out, int out_size, void* d_ws, size_t ws_size,
                              hipStream_t stream) {
  (void)in_sizes; (void)n_in; (void)out_size; (void)ws_size;
  const float* x     = (const float*)d_in[0];
  const float* tgt   = (const float*)d_in[1];
  const float* enca  = (const float*)d_in[2];
  const float* encb  = (const float*)d_in[3];
  const int*   mask  = (const int*)d_in[4];
  const float* w_in  = (const float*)d_in[5];
  const float* b_in  = (const float*)d_in[6];
  const float* w_out = (const float*)d_in[7];
  const float* b_out = (const float*)d_in[8];

  float* out  = (float*)d_out;                       // [B,T,C]
  float* attn = out + (size_t)NB * TT * CC;          // [B,T,S]

  char* ws = (char*)d_ws;
  unsigned short* x_hi   = (unsigned short*)(ws + 0);
  unsigned short* x_lo   = (unsigned short*)(ws + 33554432L);
  unsigned short* a_t_hi = (unsigned short*)(ws + 67108864L);
  unsigned short* a_t_lo = (unsigned short*)(ws + 100663296L);
  unsigned short* b_t    = (unsigned short*)(ws + 134217728L);
  unsigned short* h_hi   = (unsigned short*)(ws + 167772160L);
  unsigned short* h_lo   = (unsigned short*)(ws + 201326592L);
  unsigned short* w_in_hi= (unsigned short*)(ws + 234881024L);
  unsigned short* w_in_lo= (unsigned short*)(ws + 236978176L);
  unsigned short* w_out_b= (unsigned short*)(ws + 239075328L);
  unsigned short* attn_b = x_hi;   // 64MB region, x dead after GEMM1
  unsigned short* pv     = h_hi;   // 32MB region, h dead after scores GEMM

  hipFuncSetAttribute(reinterpret_cast<const void*>(&k_gemm8<2>),
                      hipFuncAttributeMaxDynamicSharedMemorySize, 131072);
  hipFuncSetAttribute(reinterpret_cast<const void*>(&k_gemm8<3>),
                      hipFuncAttributeMaxDynamicSharedMemorySize, 131072);
  hipFuncSetAttribute(reinterpret_cast<const void*>(&k_split8<0>),
                      hipFuncAttributeMaxDynamicSharedMemorySize, 147456);
  hipFuncSetAttribute(reinterpret_cast<const void*>(&k_split8<1>),
                      hipFuncAttributeMaxDynamicSharedMemorySize, 147456);

  dim3 blk(256), blk512(512);
  const float S05 = 0.70710678118654752f;

  k_split<<<2048, blk, 0, stream>>>(x, x_hi, x_lo, (long)NB * TT * CC / 4);
  k_split<<<512, blk, 0, stream>>>(w_in, w_in_hi, w_in_lo, (long)EE * CC / 4);
  k_conv<<<512, blk, 0, stream>>>(w_out, w_out_b, (long)CC * EE / 4);
  k_transpose<true><<<dim3(SS / 64, EE / 64, NB), blk, 0, stream>>>(enca, a_t_hi, a_t_lo, EE, SS);
  k_transpose<false><<<dim3(EE / 64, SS / 64, NB), blk, 0, stream>>>(encb, b_t, nullptr, SS, EE);

  // GEMM1: h = (x @ w_in^T + b_in + tgt) * sqrt(0.5), split bf16 out
  k_split8<0><<<dim3(EE / 256, (NB * TT) / 128, 1), blk512, 147456, stream>>>(
      x_hi, x_lo, w_in_hi, w_in_lo, EE, CC, 0, 0, 0,
      b_in, tgt, nullptr, h_hi, h_lo, S05);

  // scores = h @ enc_a (batched), raw f32 into attn region
  k_split8<1><<<dim3(SS / 256, TT / 128, NB), blk512, 147456, stream>>>(
      h_hi, h_lo, a_t_hi, a_t_lo, SS, EE,
      (long)TT * EE, (long)SS * EE, (long)TT * SS,
      nullptr, nullptr, attn, nullptr, nullptr, 1.0f);

  // masked softmax, in-place, + bf16 copy
  k_softmax<<<NB * TT, blk, 0, stream>>>(attn, attn_b, mask);

  // pv = (attn @ enc_b) * sqrt(S), bf16 out
  k_gemm8<2><<<dim3(EE / 256, TT / 256, NB), blk512, 131072, stream>>>(
      attn_b, b_t, EE, SS,
      (long)TT * SS, (long)EE * SS, (long)TT * EE,
      nullptr, nullptr, nullptr, pv, 45.254833995939045f);

  // out = (pv @ w_out^T + b_out + x) * sqrt(0.5)
  k_gemm8<3><<<dim3(CC / 256, (NB * TT) / 256, 1), blk512, 131072, stream>>>(
      pv, w_out_b, CC, EE, 0, 0, 0,
      b_out, x, out, nullptr, S05);
}

// Round 4
// 590.326 us; speedup vs baseline: 1.1080x; 1.0076x over previous
//
#include <hip/hip_runtime.h>
#include <hip/hip_bf16.h>
#include <math.h>

#define NB 8
#define TT 2048
#define SS 2048
#define CC 1024
#define EE 1024

typedef __attribute__((ext_vector_type(8))) short short8;
typedef __attribute__((ext_vector_type(4))) float f32x4;

__device__ __forceinline__ unsigned short f2bf(float f) {
  unsigned u = __builtin_bit_cast(unsigned, f);
  u += 0x7fffu + ((u >> 16) & 1u);          // RNE
  return (unsigned short)(u >> 16);
}
__device__ __forceinline__ float bf2f(unsigned short h) {
  unsigned u = ((unsigned)h) << 16;
  return __builtin_bit_cast(float, u);
}
__device__ __forceinline__ void gload16(const void* g, void* l) {
  __builtin_amdgcn_global_load_lds((const __attribute__((address_space(1))) void*)g,
                                   (__attribute__((address_space(3))) void*)l, 16, 0, 0);
}
__device__ __forceinline__ unsigned ldsoff(const void* p) {
  return (unsigned)(size_t)(const __attribute__((address_space(3))) char*)p;
}
__device__ __forceinline__ short8 ds128(unsigned off) {
  short8 r;
  asm volatile("ds_read_b128 %0, %1" : "=v"(r) : "v"(off));
  return r;
}
// XOR swizzle: bits 4-6 ^= bits 7-9 (involution)
__device__ __forceinline__ int swzi(int x) { return x ^ (((x >> 7) & 7) << 4); }

#define WAITV(N) asm volatile("s_waitcnt vmcnt(" #N ")" ::: "memory")
#define WAITL(N) asm volatile("s_waitcnt lgkmcnt(" #N ")" ::: "memory")
#define BAR() __builtin_amdgcn_s_barrier()
#define SCH0() __builtin_amdgcn_sched_barrier(0)
#define PRIO1() __builtin_amdgcn_s_setprio(1)
#define PRIO0() __builtin_amdgcn_s_setprio(0)
#define MF(a_, b_, c_) __builtin_amdgcn_mfma_f32_16x16x32_bf16(a_, b_, c_, 0, 0, 0)

// ---------------- split f32 -> bf16 hi/lo ----------------
__global__ __launch_bounds__(256) void k_split(const float* __restrict__ in,
    unsigned short* __restrict__ hi, unsigned short* __restrict__ lo, long n4) {
  long i = (long)blockIdx.x * blockDim.x + threadIdx.x;
  long stride = (long)gridDim.x * blockDim.x;
  for (; i < n4; i += stride) {
    float4 v = ((const float4*)in)[i];
    float f[4] = {v.x, v.y, v.z, v.w};
    unsigned short hh[4], ll[4];
#pragma unroll
    for (int j = 0; j < 4; ++j) {
      hh[j] = f2bf(f[j]);
      ll[j] = f2bf(f[j] - bf2f(hh[j]));
    }
    ushort4 h; h.x = hh[0]; h.y = hh[1]; h.z = hh[2]; h.w = hh[3];
    ushort4 l; l.x = ll[0]; l.y = ll[1]; l.z = ll[2]; l.w = ll[3];
    ((ushort4*)hi)[i] = h;
    ((ushort4*)lo)[i] = l;
  }
}

// ---------------- f32 -> bf16 convert ----------------
__global__ __launch_bounds__(256) void k_conv(const float* __restrict__ in,
    unsigned short* __restrict__ out, long n4) {
  long i = (long)blockIdx.x * blockDim.x + threadIdx.x;
  long stride = (long)gridDim.x * blockDim.x;
  for (; i < n4; i += stride) {
    float4 v = ((const float4*)in)[i];
    ushort4 h; h.x = f2bf(v.x); h.y = f2bf(v.y); h.z = f2bf(v.z); h.w = f2bf(v.w);
    ((ushort4*)out)[i] = h;
  }
}

// ---------------- batched transpose f32[R,C] -> bf16 [C,R] (hi (+lo)) ----------------
template <bool SPLIT>
__global__ __launch_bounds__(256) void k_transpose(const float* __restrict__ in,
    unsigned short* __restrict__ hi, unsigned short* __restrict__ lo, int R, int C) {
  __shared__ float tile[64][65];
  int b = blockIdx.z;
  const float* inb = in + (size_t)b * R * C;
  int r0 = blockIdx.y * 64, c0 = blockIdx.x * 64;
  int t = threadIdx.x;
  int tr = t >> 4;
  int tc = (t & 15) * 4;
#pragma unroll
  for (int i = 0; i < 4; ++i) {
    int r = tr + i * 16;
    float4 v = *(const float4*)(inb + (size_t)(r0 + r) * C + (c0 + tc));
    tile[r][tc] = v.x; tile[r][tc + 1] = v.y; tile[r][tc + 2] = v.z; tile[r][tc + 3] = v.w;
  }
  __syncthreads();
  size_t ob = (size_t)b * R * C;
#pragma unroll
  for (int i = 0; i < 4; ++i) {
    int c = tr + i * 16;
    unsigned short hh[4], ll[4];
#pragma unroll
    for (int j = 0; j < 4; ++j) {
      float f = tile[tc + j][c];
      hh[j] = f2bf(f);
      if (SPLIT) ll[j] = f2bf(f - bf2f(hh[j]));
    }
    ushort4 h; h.x = hh[0]; h.y = hh[1]; h.z = hh[2]; h.w = hh[3];
    *(ushort4*)(hi + ob + (size_t)(c0 + c) * R + (r0 + tc)) = h;
    if (SPLIT) {
      ushort4 l; l.x = ll[0]; l.y = ll[1]; l.z = ll[2]; l.w = ll[3];
      *(ushort4*)(lo + ob + (size_t)(c0 + c) * R + (r0 + tc)) = l;
    }
  }
}

// ================= plain bf16 GEMM, 256x256 tile, BK=64, pipelined =================
template <int EPI>
__global__ __launch_bounds__(512, 2) void k_gemm8(
    const unsigned short* __restrict__ A, const unsigned short* __restrict__ B,
    int N, int K, long sA, long sB, long sC,
    const float* __restrict__ bias, const float* __restrict__ addend,
    float* __restrict__ outF, unsigned short* __restrict__ outH, float scale) {
  extern __shared__ char lds[];
  const int tid = threadIdx.x, wave = tid >> 6, lane = tid & 63;
  const int b = blockIdx.z;
  const int m0 = blockIdx.y * 256, n0 = blockIdx.x * 256;
  const int wm = wave >> 2, wn = wave & 3;
  const unsigned short* gA = A + (size_t)b * sA + (size_t)m0 * K;
  const unsigned short* gB = B + (size_t)b * sB + (size_t)n0 * K;
  const unsigned ldsB = ldsoff(lds);

  int srow[2], sk8[2];
#pragma unroll
  for (int s = 0; s < 2; ++s) {
    int l = swzi((s * 512 + tid) * 16);
    srow[s] = l >> 6;
    sk8[s] = (l >> 4) & 3;
  }
  const int aR = wm * 128 + (lane & 15);
  const int bR = wn * 64 + (lane & 15);
  const int kB = (lane >> 4) * 16;
  const int nkt = K >> 6;

  f32x4 acc[8][4] = {};

  auto STG = [&](int t, int tensor, int ks) {
    const unsigned short* g = tensor ? gB : gA;
    char* dst = lds + (t & 1) * 65536 + tensor * 32768 + ks * 16384 + wave * 1024;
    size_t gk = (size_t)t * 64 + ks * 32;
#pragma unroll
    for (int s = 0; s < 2; ++s)
      gload16(g + ((size_t)srow[s] * K + gk + sk8[s] * 8), dst + s * 8192);
  };
  auto RA = [&](int t, int ks, int mf) {
    int lin = (aR + mf * 16) * 64 + kB;
    return ds128(ldsB + (t & 1) * 65536 + ks * 16384 + swzi(lin));
  };
  auto RB = [&](int t, int ks, int nf) {
    int lin = (bR + nf * 16) * 64 + kB;
    return ds128(ldsB + (t & 1) * 65536 + 32768 + ks * 16384 + swzi(lin));
  };

  STG(0, 1, 0); STG(0, 0, 0); STG(0, 0, 1); STG(0, 1, 1);
  if (nkt > 1) { STG(1, 1, 0); STG(1, 0, 0); }

  for (int u = 0; u < nkt; ++u) {
    if (u + 1 < nkt) { WAITV(8); } else { WAITV(0); }
    BAR();
    short8 bf[4], af[4];
#pragma unroll
    for (int nf = 0; nf < 4; ++nf) bf[nf] = RB(u, 0, nf);
#pragma unroll
    for (int mf = 0; mf < 4; ++mf) af[mf] = RA(u, 0, mf);
    if (u + 1 < nkt) { STG(u + 1, 0, 1); STG(u + 1, 1, 1); }
    BAR(); WAITL(0); SCH0(); PRIO1();
#pragma unroll
    for (int mf = 0; mf < 4; ++mf)
#pragma unroll
      for (int nf = 0; nf < 4; ++nf) acc[mf][nf] = MF(af[mf], bf[nf], acc[mf][nf]);
    PRIO0(); SCH0(); BAR();
#pragma unroll
    for (int mf = 0; mf < 4; ++mf) af[mf] = RA(u, 0, mf + 4);
    if (u + 2 < nkt) STG(u + 2, 1, 0);
    BAR(); WAITL(0); SCH0(); PRIO1();
#pragma unroll
    for (int mf = 0; mf < 4; ++mf)
#pragma unroll
      for (int nf = 0; nf < 4; ++nf) acc[mf + 4][nf] = MF(af[mf], bf[nf], acc[mf + 4][nf]);
    PRIO0(); SCH0();
    if (u + 2 < nkt) { WAITV(10); } else if (u + 1 < nkt) { WAITV(8); } else { WAITV(0); }
    BAR();
#pragma unroll
    for (int nf = 0; nf < 4; ++nf) bf[nf] = RB(u, 1, nf);
#pragma unroll
    for (int mf = 0; mf < 4; ++mf) af[mf] = RA(u, 1, mf);
    if (u + 2 < nkt) STG(u + 2, 0, 0);
    BAR(); WAITL(0); SCH0(); PRIO1();
#pragma unroll
    for (int mf = 0; mf < 4; ++mf)
#pragma unroll
      for (int nf = 0; nf < 4; ++nf) acc[mf][nf] = MF(af[mf], bf[nf], acc[mf][nf]);
    PRIO0(); SCH0(); BAR();
#pragma unroll
    for (int mf = 0; mf < 4; ++mf) af[mf] = RA(u, 1, mf + 4);
    BAR(); WAITL(0); SCH0(); PRIO1();
#pragma unroll
    for (int mf = 0; mf < 4; ++mf)
#pragma unroll
      for (int nf = 0; nf < 4; ++nf) acc[mf + 4][nf] = MF(af[mf], bf[nf], acc[mf + 4][nf]);
    PRIO0(); SCH0(); BAR();
  }

  const size_t cb = (size_t)b * sC;
  const int mB = m0 + wm * 128 + ((lane >> 4) << 2);
  const int nB = n0 + wn * 64 + (lane & 15);
#pragma unroll
  for (int mf = 0; mf < 8; ++mf)
#pragma unroll
    for (int j = 0; j < 4; ++j) {
      int m = mB + mf * 16 + j;
#pragma unroll
      for (int nf = 0; nf < 4; ++nf) {
        int n = nB + nf * 16;
        float v = acc[mf][nf][j];
        size_t o = (size_t)m * N + n;
        if (EPI == 2) outH[cb + o] = f2bf(v * scale);
        else outF[o] = (v + bias[n] + addend[o]) * scale;
      }
    }
}

// ============ split (hi/lo) GEMM, 128x256 tile, BK=32, 3 products ============
// Frags-one-tile-ahead pipeline: 3 LDS buffers, prefetch distance 2, 1 barrier/tile.
// MFMA cluster for tile u uses registers read during tile u-1 (zero-wait);
// ds_reads for tile u+1 issue before the cluster and complete under it.
// EPI: 0 = h epilogue (bias+addend,*scale, split bf16 out), 1 = raw f32 out (scores)
// Buffer layout: A_hi[128][32e]@0 (8KB), A_lo@8K, B_hi[256][32e]@16K, B_lo@32K.
template <int EPI>
__global__ __launch_bounds__(512, 2) void k_split8(
    const unsigned short* __restrict__ Ah, const unsigned short* __restrict__ Al,
    const unsigned short* __restrict__ Bh, const unsigned short* __restrict__ Bl,
    int N, int K, long sA, long sB, long sC,
    const float* __restrict__ bias, const float* __restrict__ addend,
    float* __restrict__ outF, unsigned short* __restrict__ outHi,
    unsigned short* __restrict__ outLo, float scale) {
  extern __shared__ char lds[];
  const int tid = threadIdx.x, wave = tid >> 6, lane = tid & 63;
  const int b = blockIdx.z;
  const int m0 = blockIdx.y * 128, n0 = blockIdx.x * 256;
  const int wm = wave >> 2, wn = wave & 3;
  const unsigned short* gAh = Ah + (size_t)b * sA + (size_t)m0 * K;
  const unsigned short* gAl = Al + (size_t)b * sA + (size_t)m0 * K;
  const unsigned short* gBh = Bh + (size_t)b * sB + (size_t)n0 * K;
  const unsigned short* gBl = Bl + (size_t)b * sB + (size_t)n0 * K;
  const unsigned ldsB = ldsoff(lds);

  int arw, ak8, brw[2], bk8[2];
  { int l = swzi(tid * 16); arw = l >> 6; ak8 = (l >> 4) & 3; }
#pragma unroll
  for (int s = 0; s < 2; ++s) {
    int l = swzi(s * 8192 + tid * 16);
    brw[s] = l >> 6; bk8[s] = (l >> 4) & 3;
  }
  const int aR = wm * 64 + (lane & 15);
  const int bR = wn * 64 + (lane & 15);
  const int kB = (lane >> 4) * 16;
  const int nkt = K >> 5;

  f32x4 acc[4][4] = {};

  auto STG = [&](int t, int bf) {   // 6 gload16 units -> buffer bf
    char* base = lds + bf * 49152;
    size_t gk = (size_t)t * 32;
    gload16(gAh + ((size_t)arw * K + gk + ak8 * 8), base + wave * 1024);
    gload16(gBh + ((size_t)brw[0] * K + gk + bk8[0] * 8), base + 16384 + wave * 1024);
    gload16(gBh + ((size_t)brw[1] * K + gk + bk8[1] * 8), base + 24576 + wave * 1024);
    gload16(gBl + ((size_t)brw[0] * K + gk + bk8[0] * 8), base + 32768 + wave * 1024);
    gload16(gBl + ((size_t)brw[1] * K + gk + bk8[1] * 8), base + 40960 + wave * 1024);
    gload16(gAl + ((size_t)arw * K + gk + ak8 * 8), base + 8192 + wave * 1024);
  };
  auto RA = [&](int bf, int hilo, int mf) {
    int lin = (aR + mf * 16) * 64 + kB;
    return ds128(ldsB + bf * 49152 + hilo * 8192 + swzi(lin));
  };
  auto RB = [&](int bf, int hilo, int nf) {
    int lin = (bR + nf * 16) * 64 + kB;
    return ds128(ldsB + bf * 49152 + 16384 + hilo * 16384 + swzi(lin));
  };

// frag layout: f[0..3]=A_hi, f[4..7]=B_hi, f[8..11]=A_lo, f[12..15]=B_lo
#define READF(f, bfi) do {                                                     \
  _Pragma("unroll") for (int q = 0; q < 4; ++q) f[q]      = RA(bfi, 0, q);     \
  _Pragma("unroll") for (int q = 0; q < 4; ++q) f[4 + q]  = RB(bfi, 0, q);     \
  _Pragma("unroll") for (int q = 0; q < 4; ++q) f[8 + q]  = RA(bfi, 1, q);     \
  _Pragma("unroll") for (int q = 0; q < 4; ++q) f[12 + q] = RB(bfi, 1, q);     \
} while (0)

#define MFMAC(f) do {                                                          \
  PRIO1();                                                                     \
  _Pragma("unroll") for (int mi = 0; mi < 4; ++mi)                             \
  _Pragma("unroll") for (int ni = 0; ni < 4; ++ni)                             \
    acc[mi][ni] = MF(f[mi], f[4 + ni], acc[mi][ni]);                           \
  _Pragma("unroll") for (int mi = 0; mi < 4; ++mi)                             \
  _Pragma("unroll") for (int ni = 0; ni < 4; ++ni) {                           \
    acc[mi][ni] = MF(f[mi], f[12 + ni], acc[mi][ni]);                          \
    acc[mi][ni] = MF(f[8 + mi], f[4 + ni], acc[mi][ni]);                       \
  }                                                                            \
  PRIO0();                                                                     \
} while (0)

#define STEP(u, cur, nxt) do {                                                 \
  int bn_ = bc + 1; if (bn_ >= 3) bn_ -= 3;                                    \
  int bs_ = bc + 2; if (bs_ >= 3) bs_ -= 3;                                    \
  if ((u) + 2 < nkt) STG((u) + 2, bs_);                                        \
  if ((u) + 1 < nkt) {                                                         \
    if ((u) + 2 < nkt) { WAITV(6); } else { WAITV(0); }                        \
    BAR();                                                                     \
    READF(nxt, bn_);                                                           \
  }                                                                            \
  MFMAC(cur);                                                                  \
  WAITL(0); SCH0();                                                            \
  bc = bn_;                                                                    \
} while (0)

  short8 fA[16], fB[16];
  // prologue: prefetch tiles 0,1; read tile-0 frags
  STG(0, 0);
  STG(1, 1);
  WAITV(6); BAR();
  READF(fA, 0);
  WAITL(0); SCH0();

  int bc = 0;  // buffer holding tile u
  for (int u = 0; u < nkt; u += 2) {
    STEP(u, fA, fB);
    STEP(u + 1, fB, fA);
  }
#undef READF
#undef MFMAC
#undef STEP

  const size_t cb = (size_t)b * sC;
  const int mB = m0 + wm * 64 + ((lane >> 4) << 2);
  const int nB = n0 + wn * 64 + (lane & 15);
#pragma unroll
  for (int mf = 0; mf < 4; ++mf)
#pragma unroll
    for (int j = 0; j < 4; ++j) {
      int m = mB + mf * 16 + j;
#pragma unroll
      for (int nf = 0; nf < 4; ++nf) {
        int n = nB + nf * 16;
        float v = acc[mf][nf][j];
        size_t o = (size_t)m * N + n;
        if (EPI == 0) {
          v = (v + bias[n] + addend[o]) * scale;
          unsigned short hb = f2bf(v);
          outHi[o] = hb;
          outLo[o] = f2bf(v - bf2f(hb));
        } else {
          outF[cb + o] = v;
        }
      }
    }
}

// ---------------- row softmax (in-place f32) + bf16 copy ----------------
__global__ __launch_bounds__(256) void k_softmax(float* __restrict__ attn,
    unsigned short* __restrict__ attn_b, const int* __restrict__ mask) {
  __shared__ float red[8];
  long r = blockIdx.x;
  int b = (int)(r >> 11);
  float* row = attn + r * (long)SS;
  const int* mrow = mask + (long)b * SS;
  int t = threadIdx.x;
  int base = t * 8;
  float v[8];
  float4 v0 = *(const float4*)(row + base);
  float4 v1 = *(const float4*)(row + base + 4);
  v[0] = v0.x; v[1] = v0.y; v[2] = v0.z; v[3] = v0.w;
  v[4] = v1.x; v[5] = v1.y; v[6] = v1.z; v[7] = v1.w;
  int4 m0i = *(const int4*)(mrow + base);
  int4 m1i = *(const int4*)(mrow + base + 4);
  int mm[8] = {m0i.x, m0i.y, m0i.z, m0i.w, m1i.x, m1i.y, m1i.z, m1i.w};
#pragma unroll
  for (int j = 0; j < 8; ++j) if (mm[j]) v[j] = -INFINITY;
  float mx = v[0];
#pragma unroll
  for (int j = 1; j < 8; ++j) mx = fmaxf(mx, v[j]);
#pragma unroll
  for (int off = 32; off; off >>= 1) mx = fmaxf(mx, __shfl_xor(mx, off));
  int wv = t >> 6, ln = t & 63;
  if (ln == 0) red[wv] = mx;
  __syncthreads();
  mx = fmaxf(fmaxf(red[0], red[1]), fmaxf(red[2], red[3]));
  float sum = 0.f;
#pragma unroll
  for (int j = 0; j < 8; ++j) { v[j] = __expf(v[j] - mx); sum += v[j]; }
#pragma unroll
  for (int off = 32; off; off >>= 1) sum += __shfl_xor(sum, off);
  if (ln == 0) red[4 + wv] = sum;
  __syncthreads();
  sum = (red[4] + red[5]) + (red[6] + red[7]);
  float inv = 1.0f / sum;
#pragma unroll
  for (int j = 0; j < 8; ++j) v[j] *= inv;
  float4 w0; w0.x = v[0]; w0.y = v[1]; w0.z = v[2]; w0.w = v[3];
  float4 w1; w1.x = v[4]; w1.y = v[5]; w1.z = v[6]; w1.w = v[7];
  *(float4*)(row + base) = w0;
  *(float4*)(row + base + 4) = w1;
  unsigned short* brow = attn_b + r * (long)SS + base;
  ushort4 h0; h0.x = f2bf(v[0]); h0.y = f2bf(v[1]); h0.z = f2bf(v[2]); h0.w = f2bf(v[3]);
  ushort4 h1; h1.x = f2bf(v[4]); h1.y = f2bf(v[5]); h1.z = f2bf(v[6]); h1.w = f2bf(v[7]);
  *(ushort4*)(brow) = h0;
  *(ushort4*)(brow + 4) = h1;
}

extern "C" void kernel_launch(void* const* d_in, const int* in_sizes, int n_in,
                              void* d_out, int out_size, void* d_ws, size_t ws_size,
                              hipStream_t stream) {
  (void)in_sizes; (void)n_in; (void)out_size; (void)ws_size;
  const float* x     = (const float*)d_in[0];
  const float* tgt   = (const float*)d_in[1];
  const float* enca  = (const float*)d_in[2];
  const float* encb  = (const float*)d_in[3];
  const int*   mask  = (const int*)d_in[4];
  const float* w_in  = (const float*)d_in[5];
  const float* b_in  = (const float*)d_in[6];
  const float* w_out = (const float*)d_in[7];
  const float* b_out = (const float*)d_in[8];

  float* out  = (float*)d_out;                       // [B,T,C]
  float* attn = out + (size_t)NB * TT * CC;          // [B,T,S]

  char* ws = (char*)d_ws;
  unsigned short* x_hi   = (unsigned short*)(ws + 0);
  unsigned short* x_lo   = (unsigned short*)(ws + 33554432L);
  unsigned short* a_t_hi = (unsigned short*)(ws + 67108864L);
  unsigned short* a_t_lo = (unsigned short*)(ws + 100663296L);
  unsigned short* b_t    = (unsigned short*)(ws + 134217728L);
  unsigned short* h_hi   = (unsigned short*)(ws + 167772160L);
  unsigned short* h_lo   = (unsigned short*)(ws + 201326592L);
  unsigned short* w_in_hi= (unsigned short*)(ws + 234881024L);
  unsigned short* w_in_lo= (unsigned short*)(ws + 236978176L);
  unsigned short* w_out_b= (unsigned short*)(ws + 239075328L);
  unsigned short* attn_b = x_hi;   // 64MB region, x dead after GEMM1
  unsigned short* pv     = h_hi;   // 32MB region, h dead after scores GEMM

  hipFuncSetAttribute(reinterpret_cast<const void*>(&k_gemm8<2>),
                      hipFuncAttributeMaxDynamicSharedMemorySize, 131072);
  hipFuncSetAttribute(reinterpret_cast<const void*>(&k_gemm8<3>),
                      hipFuncAttributeMaxDynamicSharedMemorySize, 131072);
  hipFuncSetAttribute(reinterpret_cast<const void*>(&k_split8<0>),
                      hipFuncAttributeMaxDynamicSharedMemorySize, 147456);
  hipFuncSetAttribute(reinterpret_cast<const void*>(&k_split8<1>),
                      hipFuncAttributeMaxDynamicSharedMemorySize, 147456);

  dim3 blk(256), blk512(512);
  const float S05 = 0.70710678118654752f;

  k_split<<<2048, blk, 0, stream>>>(x, x_hi, x_lo, (long)NB * TT * CC / 4);
  k_split<<<512, blk, 0, stream>>>(w_in, w_in_hi, w_in_lo, (long)EE * CC / 4);
  k_conv<<<512, blk, 0, stream>>>(w_out, w_out_b, (long)CC * EE / 4);
  k_transpose<true><<<dim3(SS / 64, EE / 64, NB), blk, 0, stream>>>(enca, a_t_hi, a_t_lo, EE, SS);
  k_transpose<false><<<dim3(EE / 64, SS / 64, NB), blk, 0, stream>>>(encb, b_t, nullptr, SS, EE);

  // GEMM1: h = (x @ w_in^T + b_in + tgt) * sqrt(0.5), split bf16 out
  k_split8<0><<<dim3(EE / 256, (NB * TT) / 128, 1), blk512, 147456, stream>>>(
      x_hi, x_lo, w_in_hi, w_in_lo, EE, CC, 0, 0, 0,
      b_in, tgt, nullptr, h_hi, h_lo, S05);

  // scores = h @ enc_a (batched), raw f32 into attn region
  k_split8<1><<<dim3(SS / 256, TT / 128, NB), blk512, 147456, stream>>>(
      h_hi, h_lo, a_t_hi, a_t_lo, SS, EE,
      (long)TT * EE, (long)SS * EE, (long)TT * SS,
      nullptr, nullptr, attn, nullptr, nullptr, 1.0f);

  // masked softmax, in-place, + bf16 copy
  k_softmax<<<NB * TT, blk, 0, stream>>>(attn, attn_b, mask);

  // pv = (attn @ enc_b) * sqrt(S), bf16 out
  k_gemm8<2><<<dim3(EE / 256, TT / 256, NB), blk512, 131072, stream>>>(
      attn_b, b_t, EE, SS,
      (long)TT * SS, (long)EE * SS, (long)TT * EE,
      nullptr, nullptr, nullptr, pv, 45.254833995939045f);

  // out = (pv @ w_out^T + b_out + x) * sqrt(0.5)
  k_gemm8<3><<<dim3(CC / 256, (NB * TT) / 256, 1), blk512, 131072, stream>>>(
      pv, w_out_b, CC, EE, 0, 0, 0,
      b_out, x, out, nullptr, S05);
}

// Round 5
// 540.647 us; speedup vs baseline: 1.2098x; 1.0919x over previous
//
#include <hip/hip_runtime.h>
#include <hip/hip_bf16.h>
#include <math.h>

#define NB 8
#define TT 2048
#define SS 2048
#define CC 1024
#define EE 1024

typedef __attribute__((ext_vector_type(8))) short short8;
typedef __attribute__((ext_vector_type(4))) float f32x4;

__device__ __forceinline__ unsigned short f2bf(float f) {
  unsigned u = __builtin_bit_cast(unsigned, f);
  u += 0x7fffu + ((u >> 16) & 1u);          // RNE
  return (unsigned short)(u >> 16);
}
__device__ __forceinline__ float bf2f(unsigned short h) {
  unsigned u = ((unsigned)h) << 16;
  return __builtin_bit_cast(float, u);
}
__device__ __forceinline__ void gload16(const void* g, void* l) {
  __builtin_amdgcn_global_load_lds((const __attribute__((address_space(1))) void*)g,
                                   (__attribute__((address_space(3))) void*)l, 16, 0, 0);
}
__device__ __forceinline__ unsigned ldsoff(const void* p) {
  return (unsigned)(size_t)(const __attribute__((address_space(3))) char*)p;
}
__device__ __forceinline__ short8 ds128(unsigned off) {
  short8 r;
  asm volatile("ds_read_b128 %0, %1" : "=v"(r) : "v"(off));
  return r;
}
// XOR swizzle: bits 4-6 ^= bits 7-9 (involution)
__device__ __forceinline__ int swzi(int x) { return x ^ (((x >> 7) & 7) << 4); }

#define WAITV(N) asm volatile("s_waitcnt vmcnt(" #N ")" ::: "memory")
#define WAITL(N) asm volatile("s_waitcnt lgkmcnt(" #N ")" ::: "memory")
#define BAR() __builtin_amdgcn_s_barrier()
#define SCH0() __builtin_amdgcn_sched_barrier(0)
#define PRIO1() __builtin_amdgcn_s_setprio(1)
#define PRIO0() __builtin_amdgcn_s_setprio(0)
#define MF(a_, b_, c_) __builtin_amdgcn_mfma_f32_16x16x32_bf16(a_, b_, c_, 0, 0, 0)

// chunked bijective XCD swizzle: physical pid -> logical L so each XCD gets a
// contiguous chunk of logical ids. Requires nwg % 8 == 0 (all our grids).
__device__ __forceinline__ int xcd_logical() {
  int gx = gridDim.x, gy = gridDim.y, gz = gridDim.z;
  int pid = blockIdx.x + gx * (blockIdx.y + gy * blockIdx.z);
  int q = (gx * gy * gz) >> 3;
  return (pid & 7) * q + (pid >> 3);
}

// ---------------- split f32 -> bf16 hi/lo ----------------
__global__ __launch_bounds__(256) void k_split(const float* __restrict__ in,
    unsigned short* __restrict__ hi, unsigned short* __restrict__ lo, long n4) {
  long i = (long)blockIdx.x * blockDim.x + threadIdx.x;
  long stride = (long)gridDim.x * blockDim.x;
  for (; i < n4; i += stride) {
    float4 v = ((const float4*)in)[i];
    float f[4] = {v.x, v.y, v.z, v.w};
    unsigned short hh[4], ll[4];
#pragma unroll
    for (int j = 0; j < 4; ++j) {
      hh[j] = f2bf(f[j]);
      ll[j] = f2bf(f[j] - bf2f(hh[j]));
    }
    ushort4 h; h.x = hh[0]; h.y = hh[1]; h.z = hh[2]; h.w = hh[3];
    ushort4 l; l.x = ll[0]; l.y = ll[1]; l.z = ll[2]; l.w = ll[3];
    ((ushort4*)hi)[i] = h;
    ((ushort4*)lo)[i] = l;
  }
}

// ---------------- f32 -> bf16 convert ----------------
__global__ __launch_bounds__(256) void k_conv(const float* __restrict__ in,
    unsigned short* __restrict__ out, long n4) {
  long i = (long)blockIdx.x * blockDim.x + threadIdx.x;
  long stride = (long)gridDim.x * blockDim.x;
  for (; i < n4; i += stride) {
    float4 v = ((const float4*)in)[i];
    ushort4 h; h.x = f2bf(v.x); h.y = f2bf(v.y); h.z = f2bf(v.z); h.w = f2bf(v.w);
    ((ushort4*)out)[i] = h;
  }
}

// ---------------- batched transpose f32[R,C] -> bf16 [C,R] (hi (+lo)) ----------------
template <bool SPLIT>
__global__ __launch_bounds__(256) void k_transpose(const float* __restrict__ in,
    unsigned short* __restrict__ hi, unsigned short* __restrict__ lo, int R, int C) {
  __shared__ float tile[64][65];
  int b = blockIdx.z;
  const float* inb = in + (size_t)b * R * C;
  int r0 = blockIdx.y * 64, c0 = blockIdx.x * 64;
  int t = threadIdx.x;
  int tr = t >> 4;
  int tc = (t & 15) * 4;
#pragma unroll
  for (int i = 0; i < 4; ++i) {
    int r = tr + i * 16;
    float4 v = *(const float4*)(inb + (size_t)(r0 + r) * C + (c0 + tc));
    tile[r][tc] = v.x; tile[r][tc + 1] = v.y; tile[r][tc + 2] = v.z; tile[r][tc + 3] = v.w;
  }
  __syncthreads();
  size_t ob = (size_t)b * R * C;
#pragma unroll
  for (int i = 0; i < 4; ++i) {
    int c = tr + i * 16;
    unsigned short hh[4], ll[4];
#pragma unroll
    for (int j = 0; j < 4; ++j) {
      float f = tile[tc + j][c];
      hh[j] = f2bf(f);
      if (SPLIT) ll[j] = f2bf(f - bf2f(hh[j]));
    }
    ushort4 h; h.x = hh[0]; h.y = hh[1]; h.z = hh[2]; h.w = hh[3];
    *(ushort4*)(hi + ob + (size_t)(c0 + c) * R + (r0 + tc)) = h;
    if (SPLIT) {
      ushort4 l; l.x = ll[0]; l.y = ll[1]; l.z = ll[2]; l.w = ll[3];
      *(ushort4*)(lo + ob + (size_t)(c0 + c) * R + (r0 + tc)) = l;
    }
  }
}

// ================= plain bf16 GEMM, 256x256 tile, BK=64, pipelined =================
template <int EPI>
__global__ __launch_bounds__(512, 2) void k_gemm8(
    const unsigned short* __restrict__ A, const unsigned short* __restrict__ B,
    int N, int K, long sA, long sB, long sC,
    const float* __restrict__ bias, const float* __restrict__ addend,
    float* __restrict__ outF, unsigned short* __restrict__ outH, float scale) {
  extern __shared__ char lds[];
  const int tid = threadIdx.x, wave = tid >> 6, lane = tid & 63;
  int L = xcd_logical();
  const int n0 = (L % gridDim.x) * 256;
  int tmpL = L / gridDim.x;
  const int m0 = (tmpL % gridDim.y) * 256;
  const int b = tmpL / gridDim.y;
  const int wm = wave >> 2, wn = wave & 3;
  const unsigned short* gA = A + (size_t)b * sA + (size_t)m0 * K;
  const unsigned short* gB = B + (size_t)b * sB + (size_t)n0 * K;
  const unsigned ldsB = ldsoff(lds);

  int srow[2], sk8[2];
#pragma unroll
  for (int s = 0; s < 2; ++s) {
    int l = swzi((s * 512 + tid) * 16);
    srow[s] = l >> 6;
    sk8[s] = (l >> 4) & 3;
  }
  const int aR = wm * 128 + (lane & 15);
  const int bR = wn * 64 + (lane & 15);
  const int kB = (lane >> 4) * 16;
  const int nkt = K >> 6;

  f32x4 acc[8][4] = {};

  auto STG = [&](int t, int tensor, int ks) {
    const unsigned short* g = tensor ? gB : gA;
    char* dst = lds + (t & 1) * 65536 + tensor * 32768 + ks * 16384 + wave * 1024;
    size_t gk = (size_t)t * 64 + ks * 32;
#pragma unroll
    for (int s = 0; s < 2; ++s)
      gload16(g + ((size_t)srow[s] * K + gk + sk8[s] * 8), dst + s * 8192);
  };
  auto RA = [&](int t, int ks, int mf) {
    int lin = (aR + mf * 16) * 64 + kB;
    return ds128(ldsB + (t & 1) * 65536 + ks * 16384 + swzi(lin));
  };
  auto RB = [&](int t, int ks, int nf) {
    int lin = (bR + nf * 16) * 64 + kB;
    return ds128(ldsB + (t & 1) * 65536 + 32768 + ks * 16384 + swzi(lin));
  };

  STG(0, 1, 0); STG(0, 0, 0); STG(0, 0, 1); STG(0, 1, 1);
  if (nkt > 1) { STG(1, 1, 0); STG(1, 0, 0); }

  for (int u = 0; u < nkt; ++u) {
    if (u + 1 < nkt) { WAITV(8); } else { WAITV(0); }
    BAR();
    short8 bf[4], af[4];
#pragma unroll
    for (int nf = 0; nf < 4; ++nf) bf[nf] = RB(u, 0, nf);
#pragma unroll
    for (int mf = 0; mf < 4; ++mf) af[mf] = RA(u, 0, mf);
    if (u + 1 < nkt) { STG(u + 1, 0, 1); STG(u + 1, 1, 1); }
    BAR(); WAITL(0); SCH0(); PRIO1();
#pragma unroll
    for (int mf = 0; mf < 4; ++mf)
#pragma unroll
      for (int nf = 0; nf < 4; ++nf) acc[mf][nf] = MF(af[mf], bf[nf], acc[mf][nf]);
    PRIO0(); SCH0(); BAR();
#pragma unroll
    for (int mf = 0; mf < 4; ++mf) af[mf] = RA(u, 0, mf + 4);
    if (u + 2 < nkt) STG(u + 2, 1, 0);
    BAR(); WAITL(0); SCH0(); PRIO1();
#pragma unroll
    for (int mf = 0; mf < 4; ++mf)
#pragma unroll
      for (int nf = 0; nf < 4; ++nf) acc[mf + 4][nf] = MF(af[mf], bf[nf], acc[mf + 4][nf]);
    PRIO0(); SCH0();
    if (u + 2 < nkt) { WAITV(10); } else if (u + 1 < nkt) { WAITV(8); } else { WAITV(0); }
    BAR();
#pragma unroll
    for (int nf = 0; nf < 4; ++nf) bf[nf] = RB(u, 1, nf);
#pragma unroll
    for (int mf = 0; mf < 4; ++mf) af[mf] = RA(u, 1, mf);
    if (u + 2 < nkt) STG(u + 2, 0, 0);
    BAR(); WAITL(0); SCH0(); PRIO1();
#pragma unroll
    for (int mf = 0; mf < 4; ++mf)
#pragma unroll
      for (int nf = 0; nf < 4; ++nf) acc[mf][nf] = MF(af[mf], bf[nf], acc[mf][nf]);
    PRIO0(); SCH0(); BAR();
#pragma unroll
    for (int mf = 0; mf < 4; ++mf) af[mf] = RA(u, 1, mf + 4);
    BAR(); WAITL(0); SCH0(); PRIO1();
#pragma unroll
    for (int mf = 0; mf < 4; ++mf)
#pragma unroll
      for (int nf = 0; nf < 4; ++nf) acc[mf + 4][nf] = MF(af[mf], bf[nf], acc[mf + 4][nf]);
    PRIO0(); SCH0(); BAR();
  }

  const size_t cb = (size_t)b * sC;
  const int mB = m0 + wm * 128 + ((lane >> 4) << 2);
  const int nB = n0 + wn * 64 + (lane & 15);
#pragma unroll
  for (int mf = 0; mf < 8; ++mf)
#pragma unroll
    for (int j = 0; j < 4; ++j) {
      int m = mB + mf * 16 + j;
#pragma unroll
      for (int nf = 0; nf < 4; ++nf) {
        int n = nB + nf * 16;
        float v = acc[mf][nf][j];
        size_t o = (size_t)m * N + n;
        if (EPI == 2) outH[cb + o] = f2bf(v * scale);
        else outF[o] = (v + bias[n] + addend[o]) * scale;
      }
    }
}

// ============ split (hi/lo) GEMM, 256x256 tile, BK=32, 3 products, 6 sub-phases ============
// m201-proportioned: per phase {BAR; <=8 ds_reads + stage-issue; BAR; lgkm(0); 16 MFMA}.
// Double buffer (2x64KB). Staged counted vmcnt: ph1 WAITV(4), ph3 WAITV(6), ph5 WAITV(8);
// last tile peeled with (4)/(2)/(0). Stage unit order per tile: Ah,Ah,Bh,Bh,Bl,Bl,Al,Al.
// Buffer layout (64KB): A_hi[256][32e]@0, A_lo@16K, B_hi@32K, B_lo@48K.
// EPI: 0 = h epilogue (bias+addend,*scale, split bf16 out), 1 = raw f32 out (scores)
template <int EPI>
__global__ __launch_bounds__(512, 2) void k_split8(
    const unsigned short* __restrict__ Ah, const unsigned short* __restrict__ Al,
    const unsigned short* __restrict__ Bh, const unsigned short* __restrict__ Bl,
    int N, int K, long sA, long sB, long sC,
    const float* __restrict__ bias, const float* __restrict__ addend,
    float* __restrict__ outF, unsigned short* __restrict__ outHi,
    unsigned short* __restrict__ outLo, float scale) {
  extern __shared__ char lds[];
  const int tid = threadIdx.x, wave = tid >> 6, lane = tid & 63;
  int L = xcd_logical();
  const int n0 = (L % gridDim.x) * 256;
  int tmpL = L / gridDim.x;
  const int m0 = (tmpL % gridDim.y) * 256;
  const int b = tmpL / gridDim.y;
  const int wm = wave >> 2, wn = wave & 3;
  const unsigned short* gb[4];
  gb[0] = Ah + (size_t)b * sA + (size_t)m0 * K;
  gb[1] = Al + (size_t)b * sA + (size_t)m0 * K;
  gb[2] = Bh + (size_t)b * sB + (size_t)n0 * K;
  gb[3] = Bl + (size_t)b * sB + (size_t)n0 * K;
  const unsigned ldsB = ldsoff(lds);

  // staging lane offsets (elements), shared by all 4 regions (16KB each, 2 slots)
  int soff[2];
#pragma unroll
  for (int s = 0; s < 2; ++s) {
    int l = swzi((s * 512 + tid) * 16);
    soff[s] = (l >> 6) * K + ((l >> 4) & 3) * 8;
  }
  const int aR = wm * 128 + (lane & 15);
  const int bR = wn * 64 + (lane & 15);
  const int kB = (lane >> 4) * 16;
  const int nkt = K >> 5;

  // hoisted swizzled ds cursors (lane part is mf/nf-invariant; toggle ^65536 per tile)
  unsigned vA = ldsB + (unsigned)swzi(aR * 64 + kB);
  unsigned vB = ldsB + (unsigned)swzi(bR * 64 + kB);

  f32x4 acc[8][4] = {};

  // stage one region pair (2 units) of tile t into buffer bufbase
  auto STG2 = [&](int t, unsigned bufbase, int region) {
    char* dst = lds + bufbase + region * 16384 + tid * 16;
    const unsigned short* g = gb[region] + (size_t)t * 32;
#pragma unroll
    for (int s = 0; s < 2; ++s)
      gload16(g + soff[s], dst + s * 8192);
  };

#define PH_TOP() BAR()
#define PH_MID() BAR(); WAITL(0); SCH0(); PRIO1()
#define PH_END() PRIO0(); SCH0()

#define TILE(u, WV1, WV3, WV5, STAGE) do {                                     \
  short8 ahi[8], bhi[4], blo[4], alo[4];                                       \
  /* ph1: hi*hi mf0-3 */                                                       \
  WV1; PH_TOP();                                                               \
  _Pragma("unroll") for (int q = 0; q < 4; ++q) bhi[q] = ds128(vB + 32768 + q * 1024); \
  _Pragma("unroll") for (int q = 0; q < 4; ++q) ahi[q] = ds128(vA + q * 1024); \
  if (STAGE) STG2((u) + 1, nbuf, 0);                                           \
  PH_MID();                                                                    \
  _Pragma("unroll") for (int mi = 0; mi < 4; ++mi)                             \
  _Pragma("unroll") for (int ni = 0; ni < 4; ++ni)                             \
    acc[mi][ni] = MF(ahi[mi], bhi[ni], acc[mi][ni]);                           \
  PH_END();                                                                    \
  /* ph2: hi*hi mf4-7 */                                                       \
  PH_TOP();                                                                    \
  _Pragma("unroll") for (int q = 0; q < 4; ++q) ahi[4 + q] = ds128(vA + (4 + q) * 1024); \
  if (STAGE) STG2((u) + 1, nbuf, 2);                                           \
  PH_MID();                                                                    \
  _Pragma("unroll") for (int mi = 0; mi < 4; ++mi)                             \
  _Pragma("unroll") for (int ni = 0; ni < 4; ++ni)                             \
    acc[4 + mi][ni] = MF(ahi[4 + mi], bhi[ni], acc[4 + mi][ni]);               \
  PH_END();                                                                    \
  /* ph3: hi*lo mf0-3 */                                                       \
  WV3; PH_TOP();                                                               \
  _Pragma("unroll") for (int q = 0; q < 4; ++q) blo[q] = ds128(vB + 49152 + q * 1024); \
  if (STAGE) STG2((u) + 1, nbuf, 3);                                           \
  PH_MID();                                                                    \
  _Pragma("unroll") for (int mi = 0; mi < 4; ++mi)                             \
  _Pragma("unroll") for (int ni = 0; ni < 4; ++ni)                             \
    acc[mi][ni] = MF(ahi[mi], blo[ni], acc[mi][ni]);                           \
  PH_END();                                                                    \
  /* ph4: hi*lo mf4-7 */                                                       \
  PH_TOP();                                                                    \
  if (STAGE) STG2((u) + 1, nbuf, 1);                                           \
  PH_MID();                                                                    \
  _Pragma("unroll") for (int mi = 0; mi < 4; ++mi)                             \
  _Pragma("unroll") for (int ni = 0; ni < 4; ++ni)                             \
    acc[4 + mi][ni] = MF(ahi[4 + mi], blo[ni], acc[4 + mi][ni]);               \
  PH_END();                                                                    \
  /* ph5: lo*hi mf0-3 */                                                       \
  WV5; PH_TOP();                                                               \
  _Pragma("unroll") for (int q = 0; q < 4; ++q) alo[q] = ds128(vA + 16384 + q * 1024); \
  PH_MID();                                                                    \
  _Pragma("unroll") for (int mi = 0; mi < 4; ++mi)                             \
  _Pragma("unroll") for (int ni = 0; ni < 4; ++ni)                             \
    acc[mi][ni] = MF(alo[mi], bhi[ni], acc[mi][ni]);                           \
  PH_END();                                                                    \
  /* ph6: lo*hi mf4-7 */                                                       \
  PH_TOP();                                                                    \
  _Pragma("unroll") for (int q = 0; q < 4; ++q) alo[q] = ds128(vA + 16384 + (4 + q) * 1024); \
  PH_MID();                                                                    \
  _Pragma("unroll") for (int mi = 0; mi < 4; ++mi)                             \
  _Pragma("unroll") for (int ni = 0; ni < 4; ++ni)                             \
    acc[4 + mi][ni] = MF(alo[mi], bhi[ni], acc[4 + mi][ni]);                   \
  PH_END();                                                                    \
  vA ^= 65536u; vB ^= 65536u;                                                  \
} while (0)

  // prologue: stage tile 0 into buffer 0 (unit order Ah,Ah,Bh,Bh,Bl,Bl,Al,Al)
  STG2(0, 0, 0); STG2(0, 0, 2); STG2(0, 0, 3); STG2(0, 0, 1);

  unsigned nbuf = 65536u;
  for (int u = 0; u < nkt - 1; ++u) {
    TILE(u, WAITV(4), WAITV(6), WAITV(8), 1);
    nbuf ^= 65536u;
  }
  TILE(nkt - 1, WAITV(4), WAITV(2), WAITV(0), 0);
#undef TILE
#undef PH_TOP
#undef PH_MID
#undef PH_END

  const size_t cb = (size_t)b * sC;
  const int mB = m0 + wm * 128 + ((lane >> 4) << 2);
  const int nB = n0 + wn * 64 + (lane & 15);
#pragma unroll
  for (int mf = 0; mf < 8; ++mf)
#pragma unroll
    for (int j = 0; j < 4; ++j) {
      int m = mB + mf * 16 + j;
#pragma unroll
      for (int nf = 0; nf < 4; ++nf) {
        int n = nB + nf * 16;
        float v = acc[mf][nf][j];
        size_t o = (size_t)m * N + n;
        if (EPI == 0) {
          v = (v + bias[n] + addend[o]) * scale;
          unsigned short hb = f2bf(v);
          outHi[o] = hb;
          outLo[o] = f2bf(v - bf2f(hb));
        } else {
          outF[cb + o] = v;
        }
      }
    }
}

// ---------------- row softmax (in-place f32) + bf16 copy ----------------
__global__ __launch_bounds__(256) void k_softmax(float* __restrict__ attn,
    unsigned short* __restrict__ attn_b, const int* __restrict__ mask) {
  __shared__ float red[8];
  long r = blockIdx.x;
  int b = (int)(r >> 11);
  float* row = attn + r * (long)SS;
  const int* mrow = mask + (long)b * SS;
  int t = threadIdx.x;
  int base = t * 8;
  float v[8];
  float4 v0 = *(const float4*)(row + base);
  float4 v1 = *(const float4*)(row + base + 4);
  v[0] = v0.x; v[1] = v0.y; v[2] = v0.z; v[3] = v0.w;
  v[4] = v1.x; v[5] = v1.y; v[6] = v1.z; v[7] = v1.w;
  int4 m0i = *(const int4*)(mrow + base);
  int4 m1i = *(const int4*)(mrow + base + 4);
  int mm[8] = {m0i.x, m0i.y, m0i.z, m0i.w, m1i.x, m1i.y, m1i.z, m1i.w};
#pragma unroll
  for (int j = 0; j < 8; ++j) if (mm[j]) v[j] = -INFINITY;
  float mx = v[0];
#pragma unroll
  for (int j = 1; j < 8; ++j) mx = fmaxf(mx, v[j]);
#pragma unroll
  for (int off = 32; off; off >>= 1) mx = fmaxf(mx, __shfl_xor(mx, off));
  int wv = t >> 6, ln = t & 63;
  if (ln == 0) red[wv] = mx;
  __syncthreads();
  mx = fmaxf(fmaxf(red[0], red[1]), fmaxf(red[2], red[3]));
  float sum = 0.f;
#pragma unroll
  for (int j = 0; j < 8; ++j) { v[j] = __expf(v[j] - mx); sum += v[j]; }
#pragma unroll
  for (int off = 32; off; off >>= 1) sum += __shfl_xor(sum, off);
  if (ln == 0) red[4 + wv] = sum;
  __syncthreads();
  sum = (red[4] + red[5]) + (red[6] + red[7]);
  float inv = 1.0f / sum;
#pragma unroll
  for (int j = 0; j < 8; ++j) v[j] *= inv;
  float4 w0; w0.x = v[0]; w0.y = v[1]; w0.z = v[2]; w0.w = v[3];
  float4 w1; w1.x = v[4]; w1.y = v[5]; w1.z = v[6]; w1.w = v[7];
  *(float4*)(row + base) = w0;
  *(float4*)(row + base + 4) = w1;
  unsigned short* brow = attn_b + r * (long)SS + base;
  ushort4 h0; h0.x = f2bf(v[0]); h0.y = f2bf(v[1]); h0.z = f2bf(v[2]); h0.w = f2bf(v[3]);
  ushort4 h1; h1.x = f2bf(v[4]); h1.y = f2bf(v[5]); h1.z = f2bf(v[6]); h1.w = f2bf(v[7]);
  *(ushort4*)(brow) = h0;
  *(ushort4*)(brow + 4) = h1;
}

extern "C" void kernel_launch(void* const* d_in, const int* in_sizes, int n_in,
                              void* d_out, int out_size, void* d_ws, size_t ws_size,
                              hipStream_t stream) {
  (void)in_sizes; (void)n_in; (void)out_size; (void)ws_size;
  const float* x     = (const float*)d_in[0];
  const float* tgt   = (const float*)d_in[1];
  const float* enca  = (const float*)d_in[2];
  const float* encb  = (const float*)d_in[3];
  const int*   mask  = (const int*)d_in[4];
  const float* w_in  = (const float*)d_in[5];
  const float* b_in  = (const float*)d_in[6];
  const float* w_out = (const float*)d_in[7];
  const float* b_out = (const float*)d_in[8];

  float* out  = (float*)d_out;                       // [B,T,C]
  float* attn = out + (size_t)NB * TT * CC;          // [B,T,S]

  char* ws = (char*)d_ws;
  unsigned short* x_hi   = (unsigned short*)(ws + 0);
  unsigned short* x_lo   = (unsigned short*)(ws + 33554432L);
  unsigned short* a_t_hi = (unsigned short*)(ws + 67108864L);
  unsigned short* a_t_lo = (unsigned short*)(ws + 100663296L);
  unsigned short* b_t    = (unsigned short*)(ws + 134217728L);
  unsigned short* h_hi   = (unsigned short*)(ws + 167772160L);
  unsigned short* h_lo   = (unsigned short*)(ws + 201326592L);
  unsigned short* w_in_hi= (unsigned short*)(ws + 234881024L);
  unsigned short* w_in_lo= (unsigned short*)(ws + 236978176L);
  unsigned short* w_out_b= (unsigned short*)(ws + 239075328L);
  unsigned short* attn_b = x_hi;   // 64MB region, x dead after GEMM1
  unsigned short* pv     = h_hi;   // 32MB region, h dead after scores GEMM

  hipFuncSetAttribute(reinterpret_cast<const void*>(&k_gemm8<2>),
                      hipFuncAttributeMaxDynamicSharedMemorySize, 131072);
  hipFuncSetAttribute(reinterpret_cast<const void*>(&k_gemm8<3>),
                      hipFuncAttributeMaxDynamicSharedMemorySize, 131072);
  hipFuncSetAttribute(reinterpret_cast<const void*>(&k_split8<0>),
                      hipFuncAttributeMaxDynamicSharedMemorySize, 131072);
  hipFuncSetAttribute(reinterpret_cast<const void*>(&k_split8<1>),
                      hipFuncAttributeMaxDynamicSharedMemorySize, 131072);

  dim3 blk(256), blk512(512);
  const float S05 = 0.70710678118654752f;

  k_split<<<2048, blk, 0, stream>>>(x, x_hi, x_lo, (long)NB * TT * CC / 4);
  k_split<<<512, blk, 0, stream>>>(w_in, w_in_hi, w_in_lo, (long)EE * CC / 4);
  k_conv<<<512, blk, 0, stream>>>(w_out, w_out_b, (long)CC * EE / 4);
  k_transpose<true><<<dim3(SS / 64, EE / 64, NB), blk, 0, stream>>>(enca, a_t_hi, a_t_lo, EE, SS);
  k_transpose<false><<<dim3(EE / 64, SS / 64, NB), blk, 0, stream>>>(encb, b_t, nullptr, SS, EE);

  // GEMM1: h = (x @ w_in^T + b_in + tgt) * sqrt(0.5), split bf16 out. 256 blocks, 1 round.
  k_split8<0><<<dim3(EE / 256, (NB * TT) / 256, 1), blk512, 131072, stream>>>(
      x_hi, x_lo, w_in_hi, w_in_lo, EE, CC, 0, 0, 0,
      b_in, tgt, nullptr, h_hi, h_lo, S05);

  // scores = h @ enc_a (batched), raw f32 into attn region. 512 blocks.
  k_split8<1><<<dim3(SS / 256, TT / 256, NB), blk512, 131072, stream>>>(
      h_hi, h_lo, a_t_hi, a_t_lo, SS, EE,
      (long)TT * EE, (long)SS * EE, (long)TT * SS,
      nullptr, nullptr, attn, nullptr, nullptr, 1.0f);

  // masked softmax, in-place, + bf16 copy
  k_softmax<<<NB * TT, blk, 0, stream>>>(attn, attn_b, mask);

  // pv = (attn @ enc_b) * sqrt(S), bf16 out
  k_gemm8<2><<<dim3(EE / 256, TT / 256, NB), blk512, 131072, stream>>>(
      attn_b, b_t, EE, SS,
      (long)TT * SS, (long)EE * SS, (long)TT * EE,
      nullptr, nullptr, nullptr, pv, 45.254833995939045f);

  // out = (pv @ w_out^T + b_out + x) * sqrt(0.5)
  k_gemm8<3><<<dim3(CC / 256, (NB * TT) / 256, 1), blk512, 131072, stream>>>(
      pv, w_out_b, CC, EE, 0, 0, 0,
      b_out, x, out, nullptr, S05);
}